// Round 1
// baseline (783.182 us; speedup 1.0000x reference)
//
#include <hip/hip_runtime.h>
#include <hip/hip_bf16.h>

typedef __hip_bfloat16 bf16;
typedef __attribute__((ext_vector_type(8))) __bf16 bf16x8;
typedef __attribute__((ext_vector_type(4))) float f32x4;

#define MFMA16(a, b, c) __builtin_amdgcn_mfma_f32_16x16x32_bf16((a), (b), (c), 0, 0, 0)

static __device__ __forceinline__ void gload_lds16(const void* g, void* l) {
    typedef const __attribute__((address_space(1))) unsigned gq_t;
    typedef __attribute__((address_space(3))) unsigned ls_t;
    __builtin_amdgcn_global_load_lds((gq_t*)g, (ls_t*)l, 16, 0, 0);
}

// ---------------- prepass: f32 -> bf16 cast of x ----------------
__global__ __launch_bounds__(256) void cvt_bf16_kernel(const float* __restrict__ in,
                                                       bf16* __restrict__ out, int n) {
    int i = (blockIdx.x * 256 + threadIdx.x) * 4;
    if (i < n) {
        float4 v = *reinterpret_cast<const float4*>(in + i);
        out[i + 0] = __float2bfloat16(v.x);
        out[i + 1] = __float2bfloat16(v.y);
        out[i + 2] = __float2bfloat16(v.z);
        out[i + 3] = __float2bfloat16(v.w);
    }
}

// ---------------- prepass: transpose Wq|Wk|Wv -> [3072][2048] bf16 ----------------
__global__ __launch_bounds__(256) void transpose_wqkv_kernel(const float* __restrict__ Wq,
                                                             const float* __restrict__ Wk,
                                                             const float* __restrict__ Wv,
                                                             bf16* __restrict__ out) {
    __shared__ float tile[32][33];
    int k0 = blockIdx.x * 32;   // along K (2048)
    int n0 = blockIdx.y * 32;   // along N (3072)
    int tx = threadIdx.x & 31, ty = threadIdx.x >> 5;  // 32 x 8
#pragma unroll
    for (int i = 0; i < 4; ++i) {
        int k = k0 + ty + i * 8, n = n0 + tx;
        float v;
        if (n < 2048)      v = Wq[(size_t)k * 2048 + n];
        else if (n < 2560) v = Wk[(size_t)k * 512 + (n - 2048)];
        else               v = Wv[(size_t)k * 512 + (n - 2560)];
        tile[ty + i * 8][tx] = v;
    }
    __syncthreads();
#pragma unroll
    for (int i = 0; i < 4; ++i)
        out[(size_t)(n0 + ty + i * 8) * 2048 + k0 + tx] = __float2bfloat16(tile[tx][ty + i * 8]);
}

// ---------------- prepass: transpose square W (2048x2048) -> bf16 ----------------
__global__ __launch_bounds__(256) void transpose_w_kernel(const float* __restrict__ in,
                                                          bf16* __restrict__ out) {
    __shared__ float tile[32][33];
    int k0 = blockIdx.x * 32, n0 = blockIdx.y * 32;
    int tx = threadIdx.x & 31, ty = threadIdx.x >> 5;
#pragma unroll
    for (int i = 0; i < 4; ++i)
        tile[ty + i * 8][tx] = in[(size_t)(k0 + ty + i * 8) * 2048 + n0 + tx];
    __syncthreads();
#pragma unroll
    for (int i = 0; i < 4; ++i)
        out[(size_t)(n0 + ty + i * 8) * 2048 + k0 + tx] = __float2bfloat16(tile[tx][ty + i * 8]);
}

// ---------------- GEMM: C[M,N] = A[M,K] @ BT[N,K]^T  (bf16 in, f32 acc) ----------------
template <bool OUT_F32>
__global__ __launch_bounds__(256) void gemm_bt_kernel(const bf16* __restrict__ A,
                                                      const bf16* __restrict__ BT,
                                                      void* __restrict__ Cv,
                                                      int M, int N, int K) {
    constexpr int BK = 64;
    __shared__ bf16 As[128 * BK];
    __shared__ bf16 Bs[128 * BK];
    int t = threadIdx.x;
    int lane = t & 63, w = t >> 6;
    int wr = w >> 1, wc = w & 1;
    int lr = lane & 15, lq = lane >> 4;
    int bm = blockIdx.y, bn = blockIdx.x;
    const bf16* Ab = A + (size_t)bm * 128 * K;
    const bf16* Bb = BT + (size_t)bn * 128 * K;

    f32x4 acc[4][4] = {};
    int nk = K / BK;
    for (int kt = 0; kt < nk; ++kt) {
#pragma unroll
        for (int i = 0; i < 4; ++i) {
            int idx = i * 256 + t;
            int row = idx >> 3, kc = idx & 7;
            gload_lds16(Ab + (size_t)row * K + kt * BK + kc * 8, &As[idx * 8]);
            gload_lds16(Bb + (size_t)row * K + kt * BK + kc * 8, &Bs[idx * 8]);
        }
        __syncthreads();
#pragma unroll
        for (int kk = 0; kk < 2; ++kk) {
            bf16x8 a[4], b[4];
#pragma unroll
            for (int m = 0; m < 4; ++m)
                a[m] = *reinterpret_cast<const bf16x8*>(&As[(wr * 64 + m * 16 + lr) * BK + kk * 32 + lq * 8]);
#pragma unroll
            for (int n = 0; n < 4; ++n)
                b[n] = *reinterpret_cast<const bf16x8*>(&Bs[(wc * 64 + n * 16 + lr) * BK + kk * 32 + lq * 8]);
#pragma unroll
            for (int m = 0; m < 4; ++m)
#pragma unroll
                for (int n = 0; n < 4; ++n)
                    acc[m][n] = MFMA16(a[m], b[n], acc[m][n]);
        }
        __syncthreads();
    }
#pragma unroll
    for (int m = 0; m < 4; ++m)
#pragma unroll
        for (int n = 0; n < 4; ++n) {
            int row = bm * 128 + wr * 64 + m * 16 + lq * 4;
            int col = bn * 128 + wc * 64 + n * 16 + lr;
#pragma unroll
            for (int j = 0; j < 4; ++j) {
                if (OUT_F32)
                    ((float*)Cv)[(size_t)(row + j) * N + col] = acc[m][n][j];
                else
                    ((bf16*)Cv)[(size_t)(row + j) * N + col] = __float2bfloat16(acc[m][n][j]);
            }
        }
}

// ---------------- RMSNorm + RoPE + layout; 1 wave per (row, head-slot) ----------------
// qkv [8192][3072] bf16 -> qh [B][16][L][128] (scaled by 1/16), kh [B][4][L][128], vt [B][4][128][L]
__global__ __launch_bounds__(256) void normrope_kernel(const bf16* __restrict__ qkv,
                                                       const float* __restrict__ cosT,
                                                       const float* __restrict__ sinT,
                                                       const float* __restrict__ qnw,
                                                       const float* __restrict__ knw,
                                                       bf16* __restrict__ qh,
                                                       bf16* __restrict__ kh,
                                                       bf16* __restrict__ vt) {
    int t = threadIdx.x;
    int lane = t & 63, wv = t >> 6;
    int blk = blockIdx.x;
    int r = blk / 6;
    int s = (blk % 6) * 4 + wv;     // slot 0..23: 0-15 Q heads, 16-19 K groups, 20-23 V groups
    int b = r >> 12, l = r & 4095;
    const bf16* src = qkv + (size_t)r * 3072 + s * 128;
    float x1 = __bfloat162float(src[lane]);
    float x2 = __bfloat162float(src[lane + 64]);
    if (s < 20) {
        float ss = x1 * x1 + x2 * x2;
#pragma unroll
        for (int d = 1; d < 64; d <<= 1) ss += __shfl_xor(ss, d, 64);
        float rn = rsqrtf(ss * (1.0f / 128.0f) + 1e-6f);
        const float* wn = (s < 16) ? qnw : knw;
        float xn1 = x1 * rn * wn[lane];
        float xn2 = x2 * rn * wn[lane + 64];
        float c = cosT[(size_t)l * 128 + lane];
        float sn = sinT[(size_t)l * 128 + lane];
        float o1 = xn1 * c - xn2 * sn;
        float o2 = xn2 * c + xn1 * sn;
        if (s < 16) {
            const float scl = 0.0625f;  // SCALE folded into q
            bf16* dst = qh + ((size_t)(b * 16 + s) * 4096 + l) * 128;
            dst[lane] = __float2bfloat16(o1 * scl);
            dst[lane + 64] = __float2bfloat16(o2 * scl);
        } else {
            int g = s - 16;
            bf16* dst = kh + ((size_t)(b * 4 + g) * 4096 + l) * 128;
            dst[lane] = __float2bfloat16(o1);
            dst[lane + 64] = __float2bfloat16(o2);
        }
    } else {
        int g = s - 20;
        bf16* dst = vt + (size_t)(b * 4 + g) * 128 * 4096 + l;
        dst[(size_t)lane * 4096] = __float2bfloat16(x1);
        dst[(size_t)(lane + 64) * 4096] = __float2bfloat16(x2);
    }
}

// ---------------- sliding-window flash attention ----------------
// qh [B][16][L][128] (pre-scaled), kh [B][4][L][128], vt [B][4][128][L] -> ao [B*L][2048] bf16
__global__ __launch_bounds__(256) void attn_kernel(const bf16* __restrict__ qh,
                                                   const bf16* __restrict__ kh,
                                                   const bf16* __restrict__ vt,
                                                   bf16* __restrict__ ao) {
    __shared__ bf16 P_lds[4][16][72];   // padded: row stride 144 B
    int t = threadIdx.x;
    int lane = t & 63, w = t >> 6;
    int lr = lane & 15, lq = lane >> 4;
    int qs = blockIdx.x * 64;
    int bh = blockIdx.y;
    int b = bh >> 4, h = bh & 15, g = h >> 2;
    const bf16* qp = qh + ((size_t)(b * 16 + h) * 4096 + qs + w * 16) * 128;
    const bf16* kp = kh + (size_t)(b * 4 + g) * 4096 * 128;
    const bf16* vp = vt + (size_t)(b * 4 + g) * 128 * 4096;

    bf16x8 aq[4];
#pragma unroll
    for (int kk = 0; kk < 4; ++kk)
        aq[kk] = *reinterpret_cast<const bf16x8*>(qp + (size_t)lr * 128 + kk * 32 + lq * 8);

    f32x4 o[8] = {};
    float mrun[4], lrun[4];
#pragma unroll
    for (int j = 0; j < 4; ++j) { mrun[j] = -1e30f; lrun[j] = 0.f; }
    int iq0 = qs + w * 16 + lq * 4;

    int t0 = max(0, qs - 1023) >> 6;
    int t1 = qs >> 6;
    for (int kt = t0; kt <= t1; ++kt) {
        int j0 = kt * 64;
        // ---- S = Q K^T (scale pre-folded into Q) ----
        f32x4 s[4] = {};
#pragma unroll
        for (int jt = 0; jt < 4; ++jt) {
            const bf16* kb = kp + (size_t)(j0 + jt * 16 + lr) * 128 + lq * 8;
#pragma unroll
            for (int kk = 0; kk < 4; ++kk) {
                bf16x8 bk = *reinterpret_cast<const bf16x8*>(kb + kk * 32);
                s[jt] = MFMA16(aq[kk], bk, s[jt]);
            }
        }
        // ---- sliding-window causal mask ----
#pragma unroll
        for (int jt = 0; jt < 4; ++jt)
#pragma unroll
            for (int j = 0; j < 4; ++j) {
                int qi = iq0 + j;
                int kj = j0 + jt * 16 + lr;
                if (!(kj <= qi && kj > qi - 1024)) s[jt][j] = -1e30f;
            }
        // ---- online softmax ----
        float rmax[4];
#pragma unroll
        for (int j = 0; j < 4; ++j) {
            float m0 = fmaxf(fmaxf(s[0][j], s[1][j]), fmaxf(s[2][j], s[3][j]));
#pragma unroll
            for (int d = 1; d < 16; d <<= 1) m0 = fmaxf(m0, __shfl_xor(m0, d, 64));
            rmax[j] = m0;
        }
        float sc[4], rsum[4];
#pragma unroll
        for (int j = 0; j < 4; ++j) {
            float mn = fmaxf(mrun[j], rmax[j]);
            sc[j] = __expf(mrun[j] - mn);
            mrun[j] = mn;
            float acc = 0.f;
#pragma unroll
            for (int jt = 0; jt < 4; ++jt) {
                float p = __expf(s[jt][j] - mn);
                s[jt][j] = p;
                acc += p;
            }
#pragma unroll
            for (int d = 1; d < 16; d <<= 1) acc += __shfl_xor(acc, d, 64);
            rsum[j] = acc;
            lrun[j] = lrun[j] * sc[j] + rsum[j];
        }
#pragma unroll
        for (int dt = 0; dt < 8; ++dt)
#pragma unroll
            for (int j = 0; j < 4; ++j) o[dt][j] *= sc[j];
        // ---- P -> LDS (bf16), cross quarter-wave redistribution ----
#pragma unroll
        for (int jt = 0; jt < 4; ++jt)
#pragma unroll
            for (int j = 0; j < 4; ++j)
                P_lds[w][lq * 4 + j][jt * 16 + lr] = __float2bfloat16(s[jt][j]);
        // ---- O += P V ----
#pragma unroll
        for (int kk2 = 0; kk2 < 2; ++kk2) {
            bf16x8 pa = *reinterpret_cast<const bf16x8*>(&P_lds[w][lr][kk2 * 32 + lq * 8]);
#pragma unroll
            for (int dt = 0; dt < 8; ++dt) {
                const bf16* vb = vp + (size_t)(dt * 16 + lr) * 4096 + j0 + kk2 * 32 + lq * 8;
                bf16x8 bv = *reinterpret_cast<const bf16x8*>(vb);
                o[dt] = MFMA16(pa, bv, o[dt]);
            }
        }
    }
    // ---- epilogue: O / l, write [B*L][16*128] ----
#pragma unroll
    for (int dt = 0; dt < 8; ++dt)
#pragma unroll
        for (int j = 0; j < 4; ++j) {
            float val = o[dt][j] / lrun[j];
            ao[((size_t)(b * 4096 + qs + w * 16 + lq * 4 + j)) * 2048 + h * 128 + dt * 16 + lr] =
                __float2bfloat16(val);
        }
}

extern "C" void kernel_launch(void* const* d_in, const int* in_sizes, int n_in,
                              void* d_out, int out_size, void* d_ws, size_t ws_size,
                              hipStream_t stream) {
    const float* x    = (const float*)d_in[0];
    const float* cosT = (const float*)d_in[1];
    const float* sinT = (const float*)d_in[2];
    const float* Wq   = (const float*)d_in[3];
    const float* Wk   = (const float*)d_in[4];
    const float* Wv   = (const float*)d_in[5];
    const float* Wo   = (const float*)d_in[6];
    const float* qnw  = (const float*)d_in[7];
    const float* knw  = (const float*)d_in[8];

    char* ws = (char*)d_ws;
    bf16* xb    = (bf16*)(ws);                 // 33,554,432 B  [8192][2048]
    bf16* wqkvT = (bf16*)(ws + 33554432);      // 12,582,912 B  [3072][2048]
    bf16* woT   = (bf16*)(ws + 46137344);      //  8,388,608 B  [2048][2048]
    bf16* qh    = (bf16*)(ws + 54525952);      // 33,554,432 B  [2][16][4096][128]
    bf16* kh    = (bf16*)(ws + 88080384);      //  8,388,608 B  [2][4][4096][128]
    bf16* vt    = (bf16*)(ws + 96468992);      //  8,388,608 B  [2][4][128][4096] -> total 100 MiB
    bf16* ao    = xb;                          // alias: xb dead after GEMM1
    bf16* qkv   = (bf16*)d_out;                // d_out as scratch: 50.3 MB < 64 MB, overwritten by GEMM2

    cvt_bf16_kernel<<<16384, 256, 0, stream>>>(x, xb, 16777216);
    transpose_wqkv_kernel<<<dim3(64, 96), 256, 0, stream>>>(Wq, Wk, Wv, wqkvT);
    transpose_w_kernel<<<dim3(64, 64), 256, 0, stream>>>(Wo, woT);
    gemm_bt_kernel<false><<<dim3(24, 64), 256, 0, stream>>>(xb, wqkvT, (void*)qkv, 8192, 3072, 2048);
    normrope_kernel<<<49152, 256, 0, stream>>>(qkv, cosT, sinT, qnw, knw, qh, kh, vt);
    attn_kernel<<<dim3(64, 32), 256, 0, stream>>>(qh, kh, vt, ao);
    gemm_bt_kernel<true><<<dim3(16, 64), 256, 0, stream>>>(ao, woT, d_out, 8192, 2048, 2048);
}

// Round 2
// 431.891 us; speedup vs baseline: 1.8134x; 1.8134x over previous
//
#include <hip/hip_runtime.h>
#include <hip/hip_bf16.h>

typedef __hip_bfloat16 bf16;
typedef __attribute__((ext_vector_type(8))) __bf16 bf16x8;
typedef __attribute__((ext_vector_type(4))) float f32x4;

#define MFMA16(a, b, c) __builtin_amdgcn_mfma_f32_16x16x32_bf16((a), (b), (c), 0, 0, 0)

static __device__ __forceinline__ void gload_lds16(const void* g, void* l) {
    typedef const __attribute__((address_space(1))) unsigned gq_t;
    typedef __attribute__((address_space(3))) unsigned ls_t;
    __builtin_amdgcn_global_load_lds((gq_t*)g, (ls_t*)l, 16, 0, 0);
}

// ---------------- prepass: f32 -> bf16 cast of x ----------------
__global__ __launch_bounds__(256) void cvt_bf16_kernel(const float* __restrict__ in,
                                                       bf16* __restrict__ out, int n) {
    int i = (blockIdx.x * 256 + threadIdx.x) * 4;
    if (i < n) {
        float4 v = *reinterpret_cast<const float4*>(in + i);
        out[i + 0] = __float2bfloat16(v.x);
        out[i + 1] = __float2bfloat16(v.y);
        out[i + 2] = __float2bfloat16(v.z);
        out[i + 3] = __float2bfloat16(v.w);
    }
}

// ---------------- prepass: transpose Wq|Wk|Wv -> [3072][2048] bf16 ----------------
__global__ __launch_bounds__(256) void transpose_wqkv_kernel(const float* __restrict__ Wq,
                                                             const float* __restrict__ Wk,
                                                             const float* __restrict__ Wv,
                                                             bf16* __restrict__ out) {
    __shared__ float tile[32][33];
    int k0 = blockIdx.x * 32;   // along K (2048)
    int n0 = blockIdx.y * 32;   // along N (3072)
    int tx = threadIdx.x & 31, ty = threadIdx.x >> 5;  // 32 x 8
#pragma unroll
    for (int i = 0; i < 4; ++i) {
        int k = k0 + ty + i * 8, n = n0 + tx;
        float v;
        if (n < 2048)      v = Wq[(size_t)k * 2048 + n];
        else if (n < 2560) v = Wk[(size_t)k * 512 + (n - 2048)];
        else               v = Wv[(size_t)k * 512 + (n - 2560)];
        tile[ty + i * 8][tx] = v;
    }
    __syncthreads();
#pragma unroll
    for (int i = 0; i < 4; ++i)
        out[(size_t)(n0 + ty + i * 8) * 2048 + k0 + tx] = __float2bfloat16(tile[tx][ty + i * 8]);
}

// ---------------- prepass: transpose square W (2048x2048) -> bf16 ----------------
__global__ __launch_bounds__(256) void transpose_w_kernel(const float* __restrict__ in,
                                                          bf16* __restrict__ out) {
    __shared__ float tile[32][33];
    int k0 = blockIdx.x * 32, n0 = blockIdx.y * 32;
    int tx = threadIdx.x & 31, ty = threadIdx.x >> 5;
#pragma unroll
    for (int i = 0; i < 4; ++i)
        tile[ty + i * 8][tx] = in[(size_t)(k0 + ty + i * 8) * 2048 + n0 + tx];
    __syncthreads();
#pragma unroll
    for (int i = 0; i < 4; ++i)
        out[(size_t)(n0 + ty + i * 8) * 2048 + k0 + tx] = __float2bfloat16(tile[tx][ty + i * 8]);
}

// ---------------- GEMM: C[M,N] = A[M,K] @ BT[N,K]^T  (bf16 in, f32 acc) ----------------
template <bool OUT_F32>
__global__ __launch_bounds__(256) void gemm_bt_kernel(const bf16* __restrict__ A,
                                                      const bf16* __restrict__ BT,
                                                      void* __restrict__ Cv,
                                                      int M, int N, int K) {
    constexpr int BK = 64;
    __shared__ bf16 As[128 * BK];
    __shared__ bf16 Bs[128 * BK];
    int t = threadIdx.x;
    int lane = t & 63, w = t >> 6;
    int wr = w >> 1, wc = w & 1;
    int lr = lane & 15, lq = lane >> 4;
    int bm = blockIdx.y, bn = blockIdx.x;
    const bf16* Ab = A + (size_t)bm * 128 * K;
    const bf16* Bb = BT + (size_t)bn * 128 * K;

    f32x4 acc[4][4] = {};
    int nk = K / BK;
    for (int kt = 0; kt < nk; ++kt) {
#pragma unroll
        for (int i = 0; i < 4; ++i) {
            int idx = i * 256 + t;
            int row = idx >> 3, kc = idx & 7;
            gload_lds16(Ab + (size_t)row * K + kt * BK + kc * 8, &As[idx * 8]);
            gload_lds16(Bb + (size_t)row * K + kt * BK + kc * 8, &Bs[idx * 8]);
        }
        __syncthreads();
#pragma unroll
        for (int kk = 0; kk < 2; ++kk) {
            bf16x8 a[4], b[4];
#pragma unroll
            for (int m = 0; m < 4; ++m)
                a[m] = *reinterpret_cast<const bf16x8*>(&As[(wr * 64 + m * 16 + lr) * BK + kk * 32 + lq * 8]);
#pragma unroll
            for (int n = 0; n < 4; ++n)
                b[n] = *reinterpret_cast<const bf16x8*>(&Bs[(wc * 64 + n * 16 + lr) * BK + kk * 32 + lq * 8]);
#pragma unroll
            for (int m = 0; m < 4; ++m)
#pragma unroll
                for (int n = 0; n < 4; ++n)
                    acc[m][n] = MFMA16(a[m], b[n], acc[m][n]);
        }
        __syncthreads();
    }
#pragma unroll
    for (int m = 0; m < 4; ++m)
#pragma unroll
        for (int n = 0; n < 4; ++n) {
            int row = bm * 128 + wr * 64 + m * 16 + lq * 4;
            int col = bn * 128 + wc * 64 + n * 16 + lr;
#pragma unroll
            for (int j = 0; j < 4; ++j) {
                if (OUT_F32)
                    ((float*)Cv)[(size_t)(row + j) * N + col] = acc[m][n][j];
                else
                    ((bf16*)Cv)[(size_t)(row + j) * N + col] = __float2bfloat16(acc[m][n][j]);
            }
        }
}

// ---------------- RMSNorm + RoPE + layout; 1 wave per (row, head-slot) ----------------
// qkv [8192][3072] bf16 -> qh [B][16][L][128] (scaled by 1/16),
// kh [B][4][L][128] (col XOR-swizzled per row), vt [B][4][128][L] (col-in-64-tile XOR-swizzled per row)
__global__ __launch_bounds__(256) void normrope_kernel(const bf16* __restrict__ qkv,
                                                       const float* __restrict__ cosT,
                                                       const float* __restrict__ sinT,
                                                       const float* __restrict__ qnw,
                                                       const float* __restrict__ knw,
                                                       bf16* __restrict__ qh,
                                                       bf16* __restrict__ kh,
                                                       bf16* __restrict__ vt) {
    int t = threadIdx.x;
    int lane = t & 63, wv = t >> 6;
    int blk = blockIdx.x;
    int r = blk / 6;
    int s = (blk % 6) * 4 + wv;     // slot 0..23: 0-15 Q heads, 16-19 K groups, 20-23 V groups
    int b = r >> 12, l = r & 4095;
    const bf16* src = qkv + (size_t)r * 3072 + s * 128;
    float x1 = __bfloat162float(src[lane]);
    float x2 = __bfloat162float(src[lane + 64]);
    if (s < 20) {
        float ss = x1 * x1 + x2 * x2;
#pragma unroll
        for (int d = 1; d < 64; d <<= 1) ss += __shfl_xor(ss, d, 64);
        float rn = rsqrtf(ss * (1.0f / 128.0f) + 1e-6f);
        const float* wn = (s < 16) ? qnw : knw;
        float xn1 = x1 * rn * wn[lane];
        float xn2 = x2 * rn * wn[lane + 64];
        float c = cosT[(size_t)l * 128 + lane];
        float sn = sinT[(size_t)l * 128 + lane];
        float o1 = xn1 * c - xn2 * sn;
        float o2 = xn2 * c + xn1 * sn;
        if (s < 16) {
            const float scl = 0.0625f;  // SCALE folded into q
            bf16* dst = qh + ((size_t)(b * 16 + s) * 4096 + l) * 128;
            dst[lane] = __float2bfloat16(o1 * scl);
            dst[lane + 64] = __float2bfloat16(o2 * scl);
        } else {
            int g = s - 16;
            // pre-swizzled for LDS bank-conflict-free ds_read_b128 in attn (T2 / rule #21)
            int sw = (l & 7) << 3;
            bf16* dst = kh + ((size_t)(b * 4 + g) * 4096 + l) * 128;
            dst[lane ^ sw] = __float2bfloat16(o1);
            dst[(lane + 64) ^ sw] = __float2bfloat16(o2);
        }
    } else {
        int g = s - 20;
        bf16* dst = vt + (size_t)(b * 4 + g) * 128 * 4096;
        int base = l & ~63, cj = l & 63;
        int d1 = lane, d2 = lane + 64;
        int sw = (lane & 7) << 3;   // (d1&7)==(d2&7)
        dst[(size_t)d1 * 4096 + base + (cj ^ sw)] = __float2bfloat16(x1);
        dst[(size_t)d2 * 4096 + base + (cj ^ sw)] = __float2bfloat16(x2);
    }
}

// ---------------- sliding-window flash attention ----------------
// qh [B][16][L][128] (pre-scaled), kh [B][4][L][128] (swizzled), vt [B][4][128][L] (swizzled)
// -> ao [B*L][2048] bf16
// LDS double-buffered K/V staging via global_load_lds; fixed-shift softmax (|S| <= 8.1 by
// Cauchy-Schwarz after RMSNorm) -> no running max, no per-tile reductions, no O rescale.
__global__ __launch_bounds__(256) void attn_kernel(const bf16* __restrict__ qh,
                                                   const bf16* __restrict__ kh,
                                                   const bf16* __restrict__ vt,
                                                   bf16* __restrict__ ao) {
    __shared__ bf16 Ks[2][64 * 128];
    __shared__ bf16 Vs[2][128 * 64];
    __shared__ bf16 P_lds[4][16][72];   // padded: row stride 144 B
    int t = threadIdx.x;
    int lane = t & 63, w = t >> 6;
    int lr = lane & 15, lq = lane >> 4;
    int qs = blockIdx.x * 64;
    int bh = blockIdx.y;
    int b = bh >> 4, h = bh & 15, g = h >> 2;
    const bf16* qp = qh + ((size_t)(b * 16 + h) * 4096 + qs + w * 16) * 128;
    const bf16* kp = kh + (size_t)(b * 4 + g) * 4096 * 128;
    const bf16* vp = vt + (size_t)(b * 4 + g) * 128 * 4096;

    bf16x8 aq[4];
#pragma unroll
    for (int kk = 0; kk < 4; ++kk)
        aq[kk] = *reinterpret_cast<const bf16x8*>(qp + (size_t)lr * 128 + kk * 32 + lq * 8);

    f32x4 o[8] = {};
    float lsum[4] = {0.f, 0.f, 0.f, 0.f};
    int iq0 = qs + w * 16 + lq * 4;

    int t0 = max(0, qs - 1023) >> 6;
    int t1 = qs >> 6;

    auto stage = [&](int buf, int kt) {
        int j0 = kt * 64;
        const bf16* kg = kp + (size_t)j0 * 128;   // contiguous 16 KB
#pragma unroll
        for (int i = 0; i < 4; ++i) {
            int idx = i * 256 + t;
            gload_lds16(kg + idx * 8, &Ks[buf][idx * 8]);
        }
#pragma unroll
        for (int i = 0; i < 4; ++i) {
            int idx = i * 256 + t;
            int d = idx >> 3, c = (idx & 7) * 8;
            gload_lds16(vp + (size_t)d * 4096 + j0 + c, &Vs[buf][idx * 8]);
        }
    };

    stage(0, t0);
    __syncthreads();   // compiler emits vmcnt(0) drain before s_barrier
    int cur = 0;

    for (int kt = t0; kt <= t1; ++kt) {
        int j0 = kt * 64;
        if (kt < t1) stage(cur ^ 1, kt + 1);   // prefetch overlaps compute below
        // ---- S = Q K^T from LDS (swizzled reads; scale pre-folded into Q) ----
        f32x4 s[4] = {};
#pragma unroll
        for (int jt = 0; jt < 4; ++jt) {
            int r = jt * 16 + lr;
            int rs = (r & 7) << 3;
#pragma unroll
            for (int kk = 0; kk < 4; ++kk) {
                int c = kk * 32 + lq * 8;
                bf16x8 bk = *reinterpret_cast<const bf16x8*>(&Ks[cur][r * 128 + (c ^ rs)]);
                s[jt] = MFMA16(aq[kk], bk, s[jt]);
            }
        }
        // ---- sliding-window causal mask: only boundary tiles need it ----
        if (kt == t0 || kt == t1) {
#pragma unroll
            for (int jt = 0; jt < 4; ++jt)
#pragma unroll
                for (int j = 0; j < 4; ++j) {
                    int qi = iq0 + j;
                    int kj = j0 + jt * 16 + lr;
                    if (!(kj <= qi && kj > qi - 1024)) s[jt][j] = -1e30f;
                }
        }
        // ---- fixed-shift softmax: p = exp(s - 8); defer row-sum to epilogue ----
#pragma unroll
        for (int jt = 0; jt < 4; ++jt)
#pragma unroll
            for (int j = 0; j < 4; ++j) {
                float p = __expf(s[jt][j] - 8.0f);
                lsum[j] += p;
                P_lds[w][lq * 4 + j][jt * 16 + lr] = __float2bfloat16(p);
            }
        // ---- O += P V (V from LDS, swizzled reads) ----
#pragma unroll
        for (int kk2 = 0; kk2 < 2; ++kk2) {
            bf16x8 pa = *reinterpret_cast<const bf16x8*>(&P_lds[w][lr][kk2 * 32 + lq * 8]);
#pragma unroll
            for (int dt = 0; dt < 8; ++dt) {
                int r = dt * 16 + lr;
                int c = kk2 * 32 + lq * 8;
                bf16x8 bv = *reinterpret_cast<const bf16x8*>(&Vs[cur][r * 64 + (c ^ ((r & 7) << 3))]);
                o[dt] = MFMA16(pa, bv, o[dt]);
            }
        }
        __syncthreads();   // drains this wave's staging vmcnt; all waves done with buf[cur]
        cur ^= 1;
    }
    // ---- final row-sum reduce (once, not per tile) ----
    float linv[4];
#pragma unroll
    for (int j = 0; j < 4; ++j) {
        float l = lsum[j];
        l += __shfl_xor(l, 1, 64);
        l += __shfl_xor(l, 2, 64);
        l += __shfl_xor(l, 4, 64);
        l += __shfl_xor(l, 8, 64);
        linv[j] = 1.0f / l;
    }
    // ---- epilogue: O / l, write [B*L][16*128] ----
#pragma unroll
    for (int dt = 0; dt < 8; ++dt)
#pragma unroll
        for (int j = 0; j < 4; ++j) {
            float val = o[dt][j] * linv[j];
            ao[((size_t)(b * 4096 + qs + w * 16 + lq * 4 + j)) * 2048 + h * 128 + dt * 16 + lr] =
                __float2bfloat16(val);
        }
}

extern "C" void kernel_launch(void* const* d_in, const int* in_sizes, int n_in,
                              void* d_out, int out_size, void* d_ws, size_t ws_size,
                              hipStream_t stream) {
    const float* x    = (const float*)d_in[0];
    const float* cosT = (const float*)d_in[1];
    const float* sinT = (const float*)d_in[2];
    const float* Wq   = (const float*)d_in[3];
    const float* Wk   = (const float*)d_in[4];
    const float* Wv   = (const float*)d_in[5];
    const float* Wo   = (const float*)d_in[6];
    const float* qnw  = (const float*)d_in[7];
    const float* knw  = (const float*)d_in[8];

    char* ws = (char*)d_ws;
    bf16* xb    = (bf16*)(ws);                 // 33,554,432 B  [8192][2048]
    bf16* wqkvT = (bf16*)(ws + 33554432);      // 12,582,912 B  [3072][2048]
    bf16* woT   = (bf16*)(ws + 46137344);      //  8,388,608 B  [2048][2048]
    bf16* qh    = (bf16*)(ws + 54525952);      // 33,554,432 B  [2][16][4096][128]
    bf16* kh    = (bf16*)(ws + 88080384);      //  8,388,608 B  [2][4][4096][128]
    bf16* vt    = (bf16*)(ws + 96468992);      //  8,388,608 B  [2][4][128][4096] -> total 100 MiB
    bf16* ao    = xb;                          // alias: xb dead after GEMM1
    bf16* qkv   = (bf16*)d_out;                // d_out as scratch: overwritten by GEMM2

    cvt_bf16_kernel<<<16384, 256, 0, stream>>>(x, xb, 16777216);
    transpose_wqkv_kernel<<<dim3(64, 96), 256, 0, stream>>>(Wq, Wk, Wv, wqkvT);
    transpose_w_kernel<<<dim3(64, 64), 256, 0, stream>>>(Wo, woT);
    gemm_bt_kernel<false><<<dim3(24, 64), 256, 0, stream>>>(xb, wqkvT, (void*)qkv, 8192, 3072, 2048);
    normrope_kernel<<<49152, 256, 0, stream>>>(qkv, cosT, sinT, qnw, knw, qh, kh, vt);
    attn_kernel<<<dim3(64, 32), 256, 0, stream>>>(qh, kh, vt, ao);
    gemm_bt_kernel<true><<<dim3(16, 64), 256, 0, stream>>>(ao, woT, d_out, 8192, 2048, 2048);
}

// Round 3
// 416.774 us; speedup vs baseline: 1.8792x; 1.0363x over previous
//
#include <hip/hip_runtime.h>
#include <hip/hip_bf16.h>

typedef __hip_bfloat16 bf16;
typedef __attribute__((ext_vector_type(8))) __bf16 bf16x8;
typedef __attribute__((ext_vector_type(4))) float f32x4;

#define MFMA16(a, b, c) __builtin_amdgcn_mfma_f32_16x16x32_bf16((a), (b), (c), 0, 0, 0)

static __device__ __forceinline__ void gload_lds16(const void* g, void* l) {
    typedef const __attribute__((address_space(1))) unsigned gq_t;
    typedef __attribute__((address_space(3))) unsigned ls_t;
    __builtin_amdgcn_global_load_lds((gq_t*)g, (ls_t*)l, 16, 0, 0);
}

// ---------------- prepass: f32 -> bf16 cast of x ----------------
__global__ __launch_bounds__(256) void cvt_bf16_kernel(const float* __restrict__ in,
                                                       bf16* __restrict__ out, int n) {
    int i = (blockIdx.x * 256 + threadIdx.x) * 4;
    if (i < n) {
        float4 v = *reinterpret_cast<const float4*>(in + i);
        out[i + 0] = __float2bfloat16(v.x);
        out[i + 1] = __float2bfloat16(v.y);
        out[i + 2] = __float2bfloat16(v.z);
        out[i + 3] = __float2bfloat16(v.w);
    }
}

// ---------------- prepass: transpose Wq|Wk|Wv -> [3072][2048] bf16 ----------------
__global__ __launch_bounds__(256) void transpose_wqkv_kernel(const float* __restrict__ Wq,
                                                             const float* __restrict__ Wk,
                                                             const float* __restrict__ Wv,
                                                             bf16* __restrict__ out) {
    __shared__ float tile[32][33];
    int k0 = blockIdx.x * 32;   // along K (2048)
    int n0 = blockIdx.y * 32;   // along N (3072)
    int tx = threadIdx.x & 31, ty = threadIdx.x >> 5;  // 32 x 8
#pragma unroll
    for (int i = 0; i < 4; ++i) {
        int k = k0 + ty + i * 8, n = n0 + tx;
        float v;
        if (n < 2048)      v = Wq[(size_t)k * 2048 + n];
        else if (n < 2560) v = Wk[(size_t)k * 512 + (n - 2048)];
        else               v = Wv[(size_t)k * 512 + (n - 2560)];
        tile[ty + i * 8][tx] = v;
    }
    __syncthreads();
#pragma unroll
    for (int i = 0; i < 4; ++i)
        out[(size_t)(n0 + ty + i * 8) * 2048 + k0 + tx] = __float2bfloat16(tile[tx][ty + i * 8]);
}

// ---------------- prepass: transpose square W (2048x2048) -> bf16 ----------------
__global__ __launch_bounds__(256) void transpose_w_kernel(const float* __restrict__ in,
                                                          bf16* __restrict__ out) {
    __shared__ float tile[32][33];
    int k0 = blockIdx.x * 32, n0 = blockIdx.y * 32;
    int tx = threadIdx.x & 31, ty = threadIdx.x >> 5;
#pragma unroll
    for (int i = 0; i < 4; ++i)
        tile[ty + i * 8][tx] = in[(size_t)(k0 + ty + i * 8) * 2048 + n0 + tx];
    __syncthreads();
#pragma unroll
    for (int i = 0; i < 4; ++i)
        out[(size_t)(n0 + ty + i * 8) * 2048 + k0 + tx] = __float2bfloat16(tile[tx][ty + i * 8]);
}

// ---------------- GEMM: C[M,N] = A[M,K] @ BT[N,K]^T  (bf16 in, f32 acc) ----------------
// 1D grid with bijective XCD-chunked swizzle (requires gridDim.x % 8 == 0).
template <bool OUT_F32>
__global__ __launch_bounds__(256) void gemm_bt_kernel(const bf16* __restrict__ A,
                                                      const bf16* __restrict__ BT,
                                                      void* __restrict__ Cv,
                                                      int M, int N, int K, int nbn) {
    constexpr int BK = 64;
    __shared__ bf16 As[128 * BK];
    __shared__ bf16 Bs[128 * BK];
    int lin = blockIdx.x;
    int cpx = gridDim.x >> 3;                       // blocks per XCD chunk
    int wg = (lin & 7) * cpx + (lin >> 3);          // XCD-contiguous remap
    int bm = wg / nbn, bn = wg % nbn;
    int t = threadIdx.x;
    int lane = t & 63, w = t >> 6;
    int wr = w >> 1, wc = w & 1;
    int lr = lane & 15, lq = lane >> 4;
    const bf16* Ab = A + (size_t)bm * 128 * K;
    const bf16* Bb = BT + (size_t)bn * 128 * K;

    f32x4 acc[4][4] = {};
    int nk = K / BK;
    for (int kt = 0; kt < nk; ++kt) {
#pragma unroll
        for (int i = 0; i < 4; ++i) {
            int idx = i * 256 + t;
            int row = idx >> 3, kc = idx & 7;
            gload_lds16(Ab + (size_t)row * K + kt * BK + kc * 8, &As[idx * 8]);
            gload_lds16(Bb + (size_t)row * K + kt * BK + kc * 8, &Bs[idx * 8]);
        }
        __syncthreads();
#pragma unroll
        for (int kk = 0; kk < 2; ++kk) {
            bf16x8 a[4], b[4];
#pragma unroll
            for (int m = 0; m < 4; ++m)
                a[m] = *reinterpret_cast<const bf16x8*>(&As[(wr * 64 + m * 16 + lr) * BK + kk * 32 + lq * 8]);
#pragma unroll
            for (int n = 0; n < 4; ++n)
                b[n] = *reinterpret_cast<const bf16x8*>(&Bs[(wc * 64 + n * 16 + lr) * BK + kk * 32 + lq * 8]);
#pragma unroll
            for (int m = 0; m < 4; ++m)
#pragma unroll
                for (int n = 0; n < 4; ++n)
                    acc[m][n] = MFMA16(a[m], b[n], acc[m][n]);
        }
        __syncthreads();
    }
#pragma unroll
    for (int m = 0; m < 4; ++m)
#pragma unroll
        for (int n = 0; n < 4; ++n) {
            int row = bm * 128 + wr * 64 + m * 16 + lq * 4;
            int col = bn * 128 + wc * 64 + n * 16 + lr;
#pragma unroll
            for (int j = 0; j < 4; ++j) {
                if (OUT_F32)
                    ((float*)Cv)[(size_t)(row + j) * N + col] = acc[m][n][j];
                else
                    ((bf16*)Cv)[(size_t)(row + j) * N + col] = __float2bfloat16(acc[m][n][j]);
            }
        }
}

// ---------------- RMSNorm + RoPE + layout; 1 wave per (row, head-slot) ----------------
// qkv [8192][3072] bf16 -> qh [B][16][L][128] (scaled by SCALE*log2e),
// kh [B][4][L][128] (col XOR-swizzled per row), vt [B][4][128][L] (col-in-64-tile XOR-swizzled)
__global__ __launch_bounds__(256) void normrope_kernel(const bf16* __restrict__ qkv,
                                                       const float* __restrict__ cosT,
                                                       const float* __restrict__ sinT,
                                                       const float* __restrict__ qnw,
                                                       const float* __restrict__ knw,
                                                       bf16* __restrict__ qh,
                                                       bf16* __restrict__ kh,
                                                       bf16* __restrict__ vt) {
    int t = threadIdx.x;
    int lane = t & 63, wv = t >> 6;
    int blk = blockIdx.x;
    int r = blk / 6;
    int s = (blk % 6) * 4 + wv;     // slot 0..23: 0-15 Q heads, 16-19 K groups, 20-23 V groups
    int b = r >> 12, l = r & 4095;
    const bf16* src = qkv + (size_t)r * 3072 + s * 128;
    float x1 = __bfloat162float(src[lane]);
    float x2 = __bfloat162float(src[lane + 64]);
    if (s < 20) {
        float ss = x1 * x1 + x2 * x2;
#pragma unroll
        for (int d = 1; d < 64; d <<= 1) ss += __shfl_xor(ss, d, 64);
        float rn = rsqrtf(ss * (1.0f / 128.0f) + 1e-6f);
        const float* wn = (s < 16) ? qnw : knw;
        float xn1 = x1 * rn * wn[lane];
        float xn2 = x2 * rn * wn[lane + 64];
        float c = cosT[(size_t)l * 128 + lane];
        float sn = sinT[(size_t)l * 128 + lane];
        float o1 = xn1 * c - xn2 * sn;
        float o2 = xn2 * c + xn1 * sn;
        if (s < 16) {
            const float scl = 0.0625f * 1.44269504088896f;  // SCALE * log2(e) folded into q
            bf16* dst = qh + ((size_t)(b * 16 + s) * 4096 + l) * 128;
            dst[lane] = __float2bfloat16(o1 * scl);
            dst[lane + 64] = __float2bfloat16(o2 * scl);
        } else {
            int g = s - 16;
            // pre-swizzled for LDS bank-conflict-free ds_read_b128 in attn (T2 / rule #21)
            int sw = (l & 7) << 3;
            bf16* dst = kh + ((size_t)(b * 4 + g) * 4096 + l) * 128;
            dst[lane ^ sw] = __float2bfloat16(o1);
            dst[(lane + 64) ^ sw] = __float2bfloat16(o2);
        }
    } else {
        int g = s - 20;
        bf16* dst = vt + (size_t)(b * 4 + g) * 128 * 4096;
        int base = l & ~63, cj = l & 63;
        int d1 = lane, d2 = lane + 64;
        int sw = (lane & 7) << 3;   // (d1&7)==(d2&7)
        dst[(size_t)d1 * 4096 + base + (cj ^ sw)] = __float2bfloat16(x1);
        dst[(size_t)d2 * 4096 + base + (cj ^ sw)] = __float2bfloat16(x2);
    }
}

// ---------------- sliding-window flash attention ----------------
// QBLK=128, 8 waves (512 thr), KVBLK=64, dbuf LDS staging, fixed-shift exp2 softmax.
// qh [B][16][L][128] (pre-scaled by SCALE*log2e), kh (swizzled), vt (swizzled) -> ao [B*L][2048]
__global__ __launch_bounds__(512, 4) void attn_kernel(const bf16* __restrict__ qh,
                                                      const bf16* __restrict__ kh,
                                                      const bf16* __restrict__ vt,
                                                      bf16* __restrict__ ao) {
    __shared__ bf16 Ks[2][64 * 128];    // 32 KiB
    __shared__ bf16 Vs[2][128 * 64];    // 32 KiB
    __shared__ bf16 P_lds[8][16][64];   // 16 KiB (XOR-swizzled, no pad) -> 80 KiB total
    int t = threadIdx.x;
    int lane = t & 63, w = t >> 6;
    int lr = lane & 15, lq = lane >> 4;
    int qs = blockIdx.x * 128;
    int bh = blockIdx.y;
    int b = bh >> 4, h = bh & 15, g = h >> 2;
    const bf16* qp = qh + ((size_t)(b * 16 + h) * 4096 + qs + w * 16) * 128;
    const bf16* kp = kh + (size_t)(b * 4 + g) * 4096 * 128;
    const bf16* vp = vt + (size_t)(b * 4 + g) * 128 * 4096;

    bf16x8 aq[4];
#pragma unroll
    for (int kk = 0; kk < 4; ++kk)
        aq[kk] = *reinterpret_cast<const bf16x8*>(qp + (size_t)lr * 128 + kk * 32 + lq * 8);

    f32x4 o[8] = {};
    float lsum[4] = {0.f, 0.f, 0.f, 0.f};
    int row0 = qs + w * 16;                      // wave's first q row
    int iq0 = row0 + lq * 4;
    int t0w = max(0, row0 - 1023) >> 6;          // wave's first needed tile
    int t1w = row0 >> 6;                         // wave's diagonal tile
    int t0 = max(0, qs - 1023) >> 6;             // block-level range
    int t1 = (qs + 112) >> 6;

    auto stage = [&](int buf, int kt) {
        int j0 = kt * 64;
        const bf16* kg = kp + (size_t)j0 * 128;  // contiguous 16 KB (pre-swizzled)
#pragma unroll
        for (int i = 0; i < 2; ++i) {
            int c = i * 512 + t;                 // 0..1023 chunks of 16B
            gload_lds16(kg + c * 8, &Ks[buf][c * 8]);
        }
#pragma unroll
        for (int i = 0; i < 2; ++i) {
            int c = i * 512 + t;
            int d = c >> 3, co = (c & 7) * 8;
            gload_lds16(vp + (size_t)d * 4096 + j0 + co, &Vs[buf][c * 8]);
        }
    };

    stage(0, t0);
    __syncthreads();   // compiler emits vmcnt(0) drain before s_barrier
    int cur = 0;

    for (int kt = t0; kt <= t1; ++kt) {
        int j0 = kt * 64;
        if (kt < t1) stage(cur ^ 1, kt + 1);     // prefetch overlaps compute (all waves)
        if (kt >= t0w && kt <= t1w) {            // wave-uniform activity window
            // ---- S = Q K^T from LDS (swizzled reads) ----
            f32x4 s[4] = {};
            __builtin_amdgcn_s_setprio(1);
#pragma unroll
            for (int jt = 0; jt < 4; ++jt) {
                int r = jt * 16 + lr;
                int rs = (r & 7) << 3;
#pragma unroll
                for (int kk = 0; kk < 4; ++kk) {
                    int c = kk * 32 + lq * 8;
                    bf16x8 bk = *reinterpret_cast<const bf16x8*>(&Ks[cur][r * 128 + (c ^ rs)]);
                    s[jt] = MFMA16(aq[kk], bk, s[jt]);
                }
            }
            __builtin_amdgcn_s_setprio(0);
            // ---- sliding-window causal mask: only wave-boundary tiles ----
            if (kt <= t0w + 1 || kt == t1w) {
#pragma unroll
                for (int jt = 0; jt < 4; ++jt)
#pragma unroll
                    for (int j = 0; j < 4; ++j) {
                        int qi = iq0 + j;
                        int kj = j0 + jt * 16 + lr;
                        if (!(kj <= qi && kj > qi - 1024)) s[jt][j] = -1e30f;
                    }
            }
            // ---- fixed-shift softmax in log2 space: p = exp2(s - 11.54); sum deferred ----
#pragma unroll
            for (int jt = 0; jt < 4; ++jt)
#pragma unroll
                for (int j = 0; j < 4; ++j) {
                    float p = exp2f(s[jt][j] - 11.5415603f);
                    lsum[j] += p;
                    int row = lq * 4 + j;
                    P_lds[w][row][(jt * 16 + lr) ^ ((row & 7) << 3)] = __float2bfloat16(p);
                }
            // ---- O += P V (V from LDS, swizzled reads) ----
            __builtin_amdgcn_s_setprio(1);
#pragma unroll
            for (int kk2 = 0; kk2 < 2; ++kk2) {
                bf16x8 pa = *reinterpret_cast<const bf16x8*>(
                    &P_lds[w][lr][(kk2 * 32 + lq * 8) ^ ((lr & 7) << 3)]);
#pragma unroll
                for (int dt = 0; dt < 8; ++dt) {
                    int r = dt * 16 + lr;
                    int c = kk2 * 32 + lq * 8;
                    bf16x8 bv = *reinterpret_cast<const bf16x8*>(&Vs[cur][r * 64 + (c ^ ((r & 7) << 3))]);
                    o[dt] = MFMA16(pa, bv, o[dt]);
                }
            }
            __builtin_amdgcn_s_setprio(0);
        }
        __syncthreads();   // drains staging vmcnt; all waves done with buf[cur]
        cur ^= 1;
    }
    // ---- final row-sum reduce (once, not per tile) ----
    float linv[4];
#pragma unroll
    for (int j = 0; j < 4; ++j) {
        float l = lsum[j];
        l += __shfl_xor(l, 1, 64);
        l += __shfl_xor(l, 2, 64);
        l += __shfl_xor(l, 4, 64);
        l += __shfl_xor(l, 8, 64);
        linv[j] = 1.0f / l;
    }
    // ---- epilogue: O / l, write [B*L][16*128] ----
#pragma unroll
    for (int dt = 0; dt < 8; ++dt)
#pragma unroll
        for (int j = 0; j < 4; ++j) {
            float val = o[dt][j] * linv[j];
            ao[((size_t)(b * 4096 + qs + w * 16 + lq * 4 + j)) * 2048 + h * 128 + dt * 16 + lr] =
                __float2bfloat16(val);
        }
}

extern "C" void kernel_launch(void* const* d_in, const int* in_sizes, int n_in,
                              void* d_out, int out_size, void* d_ws, size_t ws_size,
                              hipStream_t stream) {
    const float* x    = (const float*)d_in[0];
    const float* cosT = (const float*)d_in[1];
    const float* sinT = (const float*)d_in[2];
    const float* Wq   = (const float*)d_in[3];
    const float* Wk   = (const float*)d_in[4];
    const float* Wv   = (const float*)d_in[5];
    const float* Wo   = (const float*)d_in[6];
    const float* qnw  = (const float*)d_in[7];
    const float* knw  = (const float*)d_in[8];

    char* ws = (char*)d_ws;
    bf16* xb    = (bf16*)(ws);                 // 33,554,432 B  [8192][2048]
    bf16* wqkvT = (bf16*)(ws + 33554432);      // 12,582,912 B  [3072][2048]
    bf16* woT   = (bf16*)(ws + 46137344);      //  8,388,608 B  [2048][2048]
    bf16* qh    = (bf16*)(ws + 54525952);      // 33,554,432 B  [2][16][4096][128]
    bf16* kh    = (bf16*)(ws + 88080384);      //  8,388,608 B  [2][4][4096][128]
    bf16* vt    = (bf16*)(ws + 96468992);      //  8,388,608 B  [2][4][128][4096] -> total 100 MiB
    bf16* ao    = xb;                          // alias: xb dead after GEMM1
    bf16* qkv   = (bf16*)d_out;                // d_out as scratch: overwritten by GEMM2

    cvt_bf16_kernel<<<16384, 256, 0, stream>>>(x, xb, 16777216);
    transpose_wqkv_kernel<<<dim3(64, 96), 256, 0, stream>>>(Wq, Wk, Wv, wqkvT);
    transpose_w_kernel<<<dim3(64, 64), 256, 0, stream>>>(Wo, woT);
    gemm_bt_kernel<false><<<1536, 256, 0, stream>>>(xb, wqkvT, (void*)qkv, 8192, 3072, 2048, 24);
    normrope_kernel<<<49152, 256, 0, stream>>>(qkv, cosT, sinT, qnw, knw, qh, kh, vt);
    attn_kernel<<<dim3(32, 32), 512, 0, stream>>>(qh, kh, vt, ao);
    gemm_bt_kernel<true><<<1024, 256, 0, stream>>>(ao, woT, d_out, 8192, 2048, 2048, 16);
}

// Round 4
// 394.059 us; speedup vs baseline: 1.9875x; 1.0576x over previous
//
#include <hip/hip_runtime.h>
#include <hip/hip_bf16.h>

typedef __hip_bfloat16 bf16;
typedef __attribute__((ext_vector_type(8))) __bf16 bf16x8;
typedef __attribute__((ext_vector_type(4))) float f32x4;

#define MFMA16(a, b, c) __builtin_amdgcn_mfma_f32_16x16x32_bf16((a), (b), (c), 0, 0, 0)

static __device__ __forceinline__ void gload_lds16(const void* g, void* l) {
    typedef const __attribute__((address_space(1))) unsigned gq_t;
    typedef __attribute__((address_space(3))) unsigned ls_t;
    __builtin_amdgcn_global_load_lds((gq_t*)g, (ls_t*)l, 16, 0, 0);
}

// ---------------- prepass: f32 -> bf16 cast of x ----------------
__global__ __launch_bounds__(256) void cvt_bf16_kernel(const float* __restrict__ in,
                                                       bf16* __restrict__ out, int n) {
    int i = (blockIdx.x * 256 + threadIdx.x) * 4;
    if (i < n) {
        float4 v = *reinterpret_cast<const float4*>(in + i);
        out[i + 0] = __float2bfloat16(v.x);
        out[i + 1] = __float2bfloat16(v.y);
        out[i + 2] = __float2bfloat16(v.z);
        out[i + 3] = __float2bfloat16(v.w);
    }
}

// ---------------- prepass: transpose Wq|Wk|Wv -> [3072][2048] bf16 ----------------
__global__ __launch_bounds__(256) void transpose_wqkv_kernel(const float* __restrict__ Wq,
                                                             const float* __restrict__ Wk,
                                                             const float* __restrict__ Wv,
                                                             bf16* __restrict__ out) {
    __shared__ float tile[32][33];
    int k0 = blockIdx.x * 32;   // along K (2048)
    int n0 = blockIdx.y * 32;   // along N (3072)
    int tx = threadIdx.x & 31, ty = threadIdx.x >> 5;  // 32 x 8
#pragma unroll
    for (int i = 0; i < 4; ++i) {
        int k = k0 + ty + i * 8, n = n0 + tx;
        float v;
        if (n < 2048)      v = Wq[(size_t)k * 2048 + n];
        else if (n < 2560) v = Wk[(size_t)k * 512 + (n - 2048)];
        else               v = Wv[(size_t)k * 512 + (n - 2560)];
        tile[ty + i * 8][tx] = v;
    }
    __syncthreads();
#pragma unroll
    for (int i = 0; i < 4; ++i)
        out[(size_t)(n0 + ty + i * 8) * 2048 + k0 + tx] = __float2bfloat16(tile[tx][ty + i * 8]);
}

// ---------------- prepass: transpose square W (2048x2048) -> bf16 ----------------
__global__ __launch_bounds__(256) void transpose_w_kernel(const float* __restrict__ in,
                                                          bf16* __restrict__ out) {
    __shared__ float tile[32][33];
    int k0 = blockIdx.x * 32, n0 = blockIdx.y * 32;
    int tx = threadIdx.x & 31, ty = threadIdx.x >> 5;
#pragma unroll
    for (int i = 0; i < 4; ++i)
        tile[ty + i * 8][tx] = in[(size_t)(k0 + ty + i * 8) * 2048 + n0 + tx];
    __syncthreads();
#pragma unroll
    for (int i = 0; i < 4; ++i)
        out[(size_t)(n0 + ty + i * 8) * 2048 + k0 + tx] = __float2bfloat16(tile[tx][ty + i * 8]);
}

// ---------------- 256x256 8-phase GEMM: C[M,N] = A[M,K] @ BT[N,K]^T ----------------
// 8 waves (2Mx4N), BK=64, dbuf 128 KiB LDS, counted vmcnt(6), per-row chunk-XOR swizzle
// applied on the GLOBAL source address (LDS linear; same XOR on ds_read side).
template <bool OUT_F32>
__global__ __launch_bounds__(512, 2) void gemm256_kernel(const bf16* __restrict__ A,
                                                         const bf16* __restrict__ BT,
                                                         void* __restrict__ Cv,
                                                         int M, int N, int K, int nbn) {
    __shared__ bf16 As[2][256 * 64];   // 64 KiB
    __shared__ bf16 Bs[2][256 * 64];   // 64 KiB
    int t = threadIdx.x;
    int lane = t & 63, w = t >> 6;
    int wm = w >> 2, wn = w & 3;       // 2 x 4 wave grid; per-wave C: 128 x 64
    int lr = lane & 15, lq = lane >> 4;
    int lin = blockIdx.x;
    int cpx = gridDim.x >> 3;          // bijective XCD-chunked swizzle (grid % 8 == 0)
    int wg = (lin & 7) * cpx + (lin >> 3);
    int bm = wg / nbn, bn = wg % nbn;
    const bf16* Ab = A + (size_t)bm * 256 * K;
    const bf16* Bb = BT + (size_t)bn * 256 * K;

    auto stageA = [&](int buf, int kt, int half) {
#pragma unroll
        for (int i = 0; i < 2; ++i) {
            int idx = i * 512 + t;             // 0..1023 16B chunks
            int r = idx >> 3, c8 = idx & 7;    // r 0..127 within half
            int row = half * 128 + r;
            gload_lds16(Ab + (size_t)row * K + kt * 64 + ((c8 ^ (r & 7)) * 8),
                        &As[buf][row * 64 + c8 * 8]);
        }
    };
    auto stageB = [&](int buf, int kt, int half) {
#pragma unroll
        for (int i = 0; i < 2; ++i) {
            int idx = i * 512 + t;
            int r = idx >> 3, c8 = idx & 7;
            int row = half * 128 + r;
            gload_lds16(Bb + (size_t)row * K + kt * 64 + ((c8 ^ (r & 7)) * 8),
                        &Bs[buf][row * 64 + c8 * 8]);
        }
    };

    f32x4 acc[8][4] = {};
    bf16x8 bq[4][2], aq1[2][2], aq2[2][2];

    auto readA = [&](bf16x8 (&dst)[2][2], int mbase, int sbuf) {
#pragma unroll
        for (int mi = 0; mi < 2; ++mi)
#pragma unroll
            for (int ks = 0; ks < 2; ++ks) {
                int ro = wm * 128 + (mbase + mi) * 16 + lr;
                int ch = (ks * 4 + lq) ^ (ro & 7);
                dst[mi][ks] = *reinterpret_cast<const bf16x8*>(&As[sbuf][ro * 64 + ch * 8]);
            }
    };
    auto mfma8 = [&](bf16x8 (&af)[2][2], int mbase) {
#pragma unroll
        for (int mi = 0; mi < 2; ++mi)
#pragma unroll
            for (int n = 0; n < 4; ++n)
#pragma unroll
                for (int ks = 0; ks < 2; ++ks)
                    acc[mbase + mi][n] = MFMA16(af[mi][ks], bq[n][ks], acc[mbase + mi][n]);
    };

    int nkt = K >> 6;
    // prologue: tile0 complete (8 loads) + A-halves of tile1 (4 loads)
    stageA(0, 0, 0); stageA(0, 0, 1); stageB(0, 0, 0); stageB(0, 0, 1);
    if (nkt > 1) { stageA(1, 1, 0); stageA(1, 1, 1); }

    for (int T = 0; T < nkt; ++T) {
        int s = T & 1, nx = s ^ 1;
        // ---- phase 1: gate + B-all + A m0-1 ----
        if (T + 1 < nkt) {
            stageB(nx, T + 1, 0);
            asm volatile("s_waitcnt vmcnt(6)" ::: "memory");   // tile T resident; 3 halves fly
        } else {
            asm volatile("s_waitcnt vmcnt(0)" ::: "memory");   // tail drain
        }
        __builtin_amdgcn_s_barrier();                          // all waves certified
#pragma unroll
        for (int n = 0; n < 4; ++n)
#pragma unroll
            for (int ks = 0; ks < 2; ++ks) {
                int ro = wn * 64 + n * 16 + lr;
                int ch = (ks * 4 + lq) ^ (ro & 7);
                bq[n][ks] = *reinterpret_cast<const bf16x8*>(&Bs[s][ro * 64 + ch * 8]);
            }
        readA(aq1, 0, s);
        asm volatile("s_waitcnt lgkmcnt(0)" ::: "memory");
        __builtin_amdgcn_s_setprio(1);
        mfma8(aq1, 0);
        __builtin_amdgcn_s_setprio(0);
        __builtin_amdgcn_s_barrier();
        // ---- phase 2: A m2-3 ----
        if (T + 1 < nkt) stageB(nx, T + 1, 1);
        readA(aq1, 2, s);
        asm volatile("s_waitcnt lgkmcnt(0)" ::: "memory");
        __builtin_amdgcn_s_setprio(1);
        mfma8(aq1, 2);
        __builtin_amdgcn_s_setprio(0);
        __builtin_amdgcn_s_barrier();
        // ---- phase 3: A m4-7 (last reads of slot s) ----
        readA(aq1, 4, s);
        readA(aq2, 6, s);
        asm volatile("s_waitcnt lgkmcnt(0)" ::: "memory");
        __builtin_amdgcn_s_setprio(1);
        mfma8(aq1, 4);
        __builtin_amdgcn_s_setprio(0);
        __builtin_amdgcn_s_barrier();                          // slot s now read-quiet
        // ---- phase 4: stage A(T+2) into freed slot s; MFMA from regs ----
        if (T + 2 < nkt) { stageA(s, T + 2, 0); stageA(s, T + 2, 1); }
        __builtin_amdgcn_s_setprio(1);
        mfma8(aq2, 6);
        __builtin_amdgcn_s_setprio(0);
        __builtin_amdgcn_s_barrier();
    }

    // ---- epilogue ----
#pragma unroll
    for (int m = 0; m < 8; ++m)
#pragma unroll
        for (int n = 0; n < 4; ++n) {
            int row = bm * 256 + wm * 128 + m * 16 + lq * 4;
            int col = bn * 256 + wn * 64 + n * 16 + lr;
#pragma unroll
            for (int j = 0; j < 4; ++j) {
                if (OUT_F32)
                    ((float*)Cv)[(size_t)(row + j) * N + col] = acc[m][n][j];
                else
                    ((bf16*)Cv)[(size_t)(row + j) * N + col] = __float2bfloat16(acc[m][n][j]);
            }
        }
}

// ---------------- RMSNorm + RoPE + layout; 1 wave per (row, head-slot) ----------------
// qkv [8192][3072] bf16 -> qh [B][16][L][128] (scaled by SCALE*log2e),
// kh [B][4][L][128] (col XOR-swizzled per row), vt [B][4][128][L] (col-in-64-tile XOR-swizzled)
__global__ __launch_bounds__(256) void normrope_kernel(const bf16* __restrict__ qkv,
                                                       const float* __restrict__ cosT,
                                                       const float* __restrict__ sinT,
                                                       const float* __restrict__ qnw,
                                                       const float* __restrict__ knw,
                                                       bf16* __restrict__ qh,
                                                       bf16* __restrict__ kh,
                                                       bf16* __restrict__ vt) {
    int t = threadIdx.x;
    int lane = t & 63, wv = t >> 6;
    int blk = blockIdx.x;
    int r = blk / 6;
    int s = (blk % 6) * 4 + wv;     // slot 0..23: 0-15 Q heads, 16-19 K groups, 20-23 V groups
    int b = r >> 12, l = r & 4095;
    const bf16* src = qkv + (size_t)r * 3072 + s * 128;
    float x1 = __bfloat162float(src[lane]);
    float x2 = __bfloat162float(src[lane + 64]);
    if (s < 20) {
        float ss = x1 * x1 + x2 * x2;
#pragma unroll
        for (int d = 1; d < 64; d <<= 1) ss += __shfl_xor(ss, d, 64);
        float rn = rsqrtf(ss * (1.0f / 128.0f) + 1e-6f);
        const float* wn = (s < 16) ? qnw : knw;
        float xn1 = x1 * rn * wn[lane];
        float xn2 = x2 * rn * wn[lane + 64];
        float c = cosT[(size_t)l * 128 + lane];
        float sn = sinT[(size_t)l * 128 + lane];
        float o1 = xn1 * c - xn2 * sn;
        float o2 = xn2 * c + xn1 * sn;
        if (s < 16) {
            const float scl = 0.0625f * 1.44269504088896f;  // SCALE * log2(e) folded into q
            bf16* dst = qh + ((size_t)(b * 16 + s) * 4096 + l) * 128;
            dst[lane] = __float2bfloat16(o1 * scl);
            dst[lane + 64] = __float2bfloat16(o2 * scl);
        } else {
            int g = s - 16;
            // pre-swizzled for LDS bank-conflict-free ds_read_b128 in attn (T2 / rule #21)
            int sw = (l & 7) << 3;
            bf16* dst = kh + ((size_t)(b * 4 + g) * 4096 + l) * 128;
            dst[lane ^ sw] = __float2bfloat16(o1);
            dst[(lane + 64) ^ sw] = __float2bfloat16(o2);
        }
    } else {
        int g = s - 20;
        bf16* dst = vt + (size_t)(b * 4 + g) * 128 * 4096;
        int base = l & ~63, cj = l & 63;
        int d1 = lane, d2 = lane + 64;
        int sw = (lane & 7) << 3;   // (d1&7)==(d2&7)
        dst[(size_t)d1 * 4096 + base + (cj ^ sw)] = __float2bfloat16(x1);
        dst[(size_t)d2 * 4096 + base + (cj ^ sw)] = __float2bfloat16(x2);
    }
}

// ---------------- sliding-window flash attention ----------------
// QBLK=128, 8 waves (512 thr), KVBLK=64, dbuf LDS staging, fixed-shift exp2 softmax.
// qh [B][16][L][128] (pre-scaled by SCALE*log2e), kh (swizzled), vt (swizzled) -> ao [B*L][2048]
__global__ __launch_bounds__(512, 4) void attn_kernel(const bf16* __restrict__ qh,
                                                      const bf16* __restrict__ kh,
                                                      const bf16* __restrict__ vt,
                                                      bf16* __restrict__ ao) {
    __shared__ bf16 Ks[2][64 * 128];    // 32 KiB
    __shared__ bf16 Vs[2][128 * 64];    // 32 KiB
    __shared__ bf16 P_lds[8][16][64];   // 16 KiB (XOR-swizzled, no pad) -> 80 KiB total
    int t = threadIdx.x;
    int lane = t & 63, w = t >> 6;
    int lr = lane & 15, lq = lane >> 4;
    int qs = blockIdx.x * 128;
    int bh = blockIdx.y;
    int b = bh >> 4, h = bh & 15, g = h >> 2;
    const bf16* qp = qh + ((size_t)(b * 16 + h) * 4096 + qs + w * 16) * 128;
    const bf16* kp = kh + (size_t)(b * 4 + g) * 4096 * 128;
    const bf16* vp = vt + (size_t)(b * 4 + g) * 128 * 4096;

    bf16x8 aq[4];
#pragma unroll
    for (int kk = 0; kk < 4; ++kk)
        aq[kk] = *reinterpret_cast<const bf16x8*>(qp + (size_t)lr * 128 + kk * 32 + lq * 8);

    f32x4 o[8] = {};
    float lsum[4] = {0.f, 0.f, 0.f, 0.f};
    int row0 = qs + w * 16;                      // wave's first q row
    int iq0 = row0 + lq * 4;
    int t0w = max(0, row0 - 1023) >> 6;          // wave's first needed tile
    int t1w = row0 >> 6;                         // wave's diagonal tile
    int t0 = max(0, qs - 1023) >> 6;             // block-level range
    int t1 = (qs + 112) >> 6;

    auto stage = [&](int buf, int kt) {
        int j0 = kt * 64;
        const bf16* kg = kp + (size_t)j0 * 128;  // contiguous 16 KB (pre-swizzled)
#pragma unroll
        for (int i = 0; i < 2; ++i) {
            int c = i * 512 + t;                 // 0..1023 chunks of 16B
            gload_lds16(kg + c * 8, &Ks[buf][c * 8]);
        }
#pragma unroll
        for (int i = 0; i < 2; ++i) {
            int c = i * 512 + t;
            int d = c >> 3, co = (c & 7) * 8;
            gload_lds16(vp + (size_t)d * 4096 + j0 + co, &Vs[buf][c * 8]);
        }
    };

    stage(0, t0);
    __syncthreads();   // compiler emits vmcnt(0) drain before s_barrier
    int cur = 0;

    for (int kt = t0; kt <= t1; ++kt) {
        int j0 = kt * 64;
        if (kt < t1) stage(cur ^ 1, kt + 1);     // prefetch overlaps compute (all waves)
        if (kt >= t0w && kt <= t1w) {            // wave-uniform activity window
            // ---- S = Q K^T from LDS (swizzled reads) ----
            f32x4 s[4] = {};
            __builtin_amdgcn_s_setprio(1);
#pragma unroll
            for (int jt = 0; jt < 4; ++jt) {
                int r = jt * 16 + lr;
                int rs = (r & 7) << 3;
#pragma unroll
                for (int kk = 0; kk < 4; ++kk) {
                    int c = kk * 32 + lq * 8;
                    bf16x8 bk = *reinterpret_cast<const bf16x8*>(&Ks[cur][r * 128 + (c ^ rs)]);
                    s[jt] = MFMA16(aq[kk], bk, s[jt]);
                }
            }
            __builtin_amdgcn_s_setprio(0);
            // ---- sliding-window causal mask: only wave-boundary tiles ----
            if (kt <= t0w + 1 || kt == t1w) {
#pragma unroll
                for (int jt = 0; jt < 4; ++jt)
#pragma unroll
                    for (int j = 0; j < 4; ++j) {
                        int qi = iq0 + j;
                        int kj = j0 + jt * 16 + lr;
                        if (!(kj <= qi && kj > qi - 1024)) s[jt][j] = -1e30f;
                    }
            }
            // ---- fixed-shift softmax in log2 space: p = exp2(s - 11.54); sum deferred ----
#pragma unroll
            for (int jt = 0; jt < 4; ++jt)
#pragma unroll
                for (int j = 0; j < 4; ++j) {
                    float p = exp2f(s[jt][j] - 11.5415603f);
                    lsum[j] += p;
                    int row = lq * 4 + j;
                    P_lds[w][row][(jt * 16 + lr) ^ ((row & 7) << 3)] = __float2bfloat16(p);
                }
            // ---- O += P V (V from LDS, swizzled reads) ----
            __builtin_amdgcn_s_setprio(1);
#pragma unroll
            for (int kk2 = 0; kk2 < 2; ++kk2) {
                bf16x8 pa = *reinterpret_cast<const bf16x8*>(
                    &P_lds[w][lr][(kk2 * 32 + lq * 8) ^ ((lr & 7) << 3)]);
#pragma unroll
                for (int dt = 0; dt < 8; ++dt) {
                    int r = dt * 16 + lr;
                    int c = kk2 * 32 + lq * 8;
                    bf16x8 bv = *reinterpret_cast<const bf16x8*>(&Vs[cur][r * 64 + (c ^ ((r & 7) << 3))]);
                    o[dt] = MFMA16(pa, bv, o[dt]);
                }
            }
            __builtin_amdgcn_s_setprio(0);
        }
        __syncthreads();   // drains staging vmcnt; all waves done with buf[cur]
        cur ^= 1;
    }
    // ---- final row-sum reduce (once, not per tile) ----
    float linv[4];
#pragma unroll
    for (int j = 0; j < 4; ++j) {
        float l = lsum[j];
        l += __shfl_xor(l, 1, 64);
        l += __shfl_xor(l, 2, 64);
        l += __shfl_xor(l, 4, 64);
        l += __shfl_xor(l, 8, 64);
        linv[j] = 1.0f / l;
    }
    // ---- epilogue: O / l, write [B*L][16*128] ----
#pragma unroll
    for (int dt = 0; dt < 8; ++dt)
#pragma unroll
        for (int j = 0; j < 4; ++j) {
            float val = o[dt][j] * linv[j];
            ao[((size_t)(b * 4096 + qs + w * 16 + lq * 4 + j)) * 2048 + h * 128 + dt * 16 + lr] =
                __float2bfloat16(val);
        }
}

extern "C" void kernel_launch(void* const* d_in, const int* in_sizes, int n_in,
                              void* d_out, int out_size, void* d_ws, size_t ws_size,
                              hipStream_t stream) {
    const float* x    = (const float*)d_in[0];
    const float* cosT = (const float*)d_in[1];
    const float* sinT = (const float*)d_in[2];
    const float* Wq   = (const float*)d_in[3];
    const float* Wk   = (const float*)d_in[4];
    const float* Wv   = (const float*)d_in[5];
    const float* Wo   = (const float*)d_in[6];
    const float* qnw  = (const float*)d_in[7];
    const float* knw  = (const float*)d_in[8];

    char* ws = (char*)d_ws;
    bf16* xb    = (bf16*)(ws);                 // 33,554,432 B  [8192][2048]
    bf16* wqkvT = (bf16*)(ws + 33554432);      // 12,582,912 B  [3072][2048]
    bf16* woT   = (bf16*)(ws + 46137344);      //  8,388,608 B  [2048][2048]
    bf16* qh    = (bf16*)(ws + 54525952);      // 33,554,432 B  [2][16][4096][128]
    bf16* kh    = (bf16*)(ws + 88080384);      //  8,388,608 B  [2][4][4096][128]
    bf16* vt    = (bf16*)(ws + 96468992);      //  8,388,608 B  [2][4][128][4096] -> total 100 MiB
    bf16* ao    = xb;                          // alias: xb dead after GEMM1
    bf16* qkv   = (bf16*)d_out;                // d_out as scratch: overwritten by GEMM2

    cvt_bf16_kernel<<<16384, 256, 0, stream>>>(x, xb, 16777216);
    transpose_wqkv_kernel<<<dim3(64, 96), 256, 0, stream>>>(Wq, Wk, Wv, wqkvT);
    transpose_w_kernel<<<dim3(64, 64), 256, 0, stream>>>(Wo, woT);
    gemm256_kernel<false><<<384, 512, 0, stream>>>(xb, wqkvT, (void*)qkv, 8192, 3072, 2048, 12);
    normrope_kernel<<<49152, 256, 0, stream>>>(qkv, cosT, sinT, qnw, knw, qh, kh, vt);
    attn_kernel<<<dim3(32, 32), 512, 0, stream>>>(qh, kh, vt, ao);
    gemm256_kernel<true><<<256, 512, 0, stream>>>(ao, woT, d_out, 8192, 2048, 2048, 8);
}

// Round 5
// 361.934 us; speedup vs baseline: 2.1639x; 1.0888x over previous
//
#include <hip/hip_runtime.h>
#include <hip/hip_bf16.h>

typedef __hip_bfloat16 bf16;
typedef __attribute__((ext_vector_type(8))) __bf16 bf16x8;
typedef __attribute__((ext_vector_type(4))) float f32x4;

#define MFMA16(a, b, c) __builtin_amdgcn_mfma_f32_16x16x32_bf16((a), (b), (c), 0, 0, 0)

static __device__ __forceinline__ void gload_lds16(const void* g, void* l) {
    typedef const __attribute__((address_space(1))) unsigned gq_t;
    typedef __attribute__((address_space(3))) unsigned ls_t;
    __builtin_amdgcn_global_load_lds((gq_t*)g, (ls_t*)l, 16, 0, 0);
}

// ---------------- prepass: f32 -> bf16 cast of x ----------------
__global__ __launch_bounds__(256) void cvt_bf16_kernel(const float* __restrict__ in,
                                                       bf16* __restrict__ out, int n) {
    int i = (blockIdx.x * 256 + threadIdx.x) * 8;
    if (i < n) {
        float4 a = *reinterpret_cast<const float4*>(in + i);
        float4 b = *reinterpret_cast<const float4*>(in + i + 4);
        bf16 tmp[8];
        tmp[0] = __float2bfloat16(a.x); tmp[1] = __float2bfloat16(a.y);
        tmp[2] = __float2bfloat16(a.z); tmp[3] = __float2bfloat16(a.w);
        tmp[4] = __float2bfloat16(b.x); tmp[5] = __float2bfloat16(b.y);
        tmp[6] = __float2bfloat16(b.z); tmp[7] = __float2bfloat16(b.w);
        *reinterpret_cast<uint4*>(out + i) = *reinterpret_cast<const uint4*>(tmp);
    }
}

// ---------------- prepass: transpose Wq|Wk|Wv -> [3072][2048] bf16 ----------------
__global__ __launch_bounds__(256) void transpose_wqkv_kernel(const float* __restrict__ Wq,
                                                             const float* __restrict__ Wk,
                                                             const float* __restrict__ Wv,
                                                             bf16* __restrict__ out) {
    __shared__ float tile[32][33];
    int k0 = blockIdx.x * 32;   // along K (2048)
    int n0 = blockIdx.y * 32;   // along N (3072)
    int tx = threadIdx.x & 31, ty = threadIdx.x >> 5;  // 32 x 8
#pragma unroll
    for (int i = 0; i < 4; ++i) {
        int k = k0 + ty + i * 8, n = n0 + tx;
        float v;
        if (n < 2048)      v = Wq[(size_t)k * 2048 + n];
        else if (n < 2560) v = Wk[(size_t)k * 512 + (n - 2048)];
        else               v = Wv[(size_t)k * 512 + (n - 2560)];
        tile[ty + i * 8][tx] = v;
    }
    __syncthreads();
#pragma unroll
    for (int i = 0; i < 4; ++i)
        out[(size_t)(n0 + ty + i * 8) * 2048 + k0 + tx] = __float2bfloat16(tile[tx][ty + i * 8]);
}

// ---------------- prepass: transpose square W (2048x2048) -> bf16 ----------------
__global__ __launch_bounds__(256) void transpose_w_kernel(const float* __restrict__ in,
                                                          bf16* __restrict__ out) {
    __shared__ float tile[32][33];
    int k0 = blockIdx.x * 32, n0 = blockIdx.y * 32;
    int tx = threadIdx.x & 31, ty = threadIdx.x >> 5;
#pragma unroll
    for (int i = 0; i < 4; ++i)
        tile[ty + i * 8][tx] = in[(size_t)(k0 + ty + i * 8) * 2048 + n0 + tx];
    __syncthreads();
#pragma unroll
    for (int i = 0; i < 4; ++i)
        out[(size_t)(n0 + ty + i * 8) * 2048 + k0 + tx] = __float2bfloat16(tile[tx][ty + i * 8]);
}

// ---------------- 8-phase GEMM template (m201-faithful): C = A[M,K] @ BT[N,K]^T ----------------
// Tile 256 x (NFRAG*64), BK=64, 8 waves (2M x 4N), per-wave C = 128 x NFRAG*16.
// Fixed slot roles: slot0 = even K-tiles, slot1 = odd. Per iter (2 K-tiles, 8 phases):
//   phase = { ds_reads(this phase); stage 512-chunk pieces; [vmcnt gate @ phi4/phi8];
//             s_barrier; lgkmcnt(0); setprio(1); MFMA cluster; setprio(0); s_barrier }
// Staging: phi1 A(T+1)x4, phi2-3 B(T+2), phi5 A(T+2)x4, phi6-7 B(T+3).
// Gates: phi4 certifies tile T+1 (vmcnt leaves B(T+2)'s PB loads); phi8 certifies T+2.
template <int NFRAG, bool OUT_F32>
__global__ __launch_bounds__(512, 2) void gemm8p_kernel(const bf16* __restrict__ A,
                                                        const bf16* __restrict__ BT,
                                                        void* __restrict__ Cv,
                                                        int M, int N, int K, int nbn) {
    constexpr int BN = NFRAG * 64;
    constexpr int PB = NFRAG;          // B pieces per K-tile (1 gload/thread each)
    __shared__ bf16 As[2][256 * 64];
    __shared__ bf16 Bs[2][BN * 64];
    int t = threadIdx.x;
    int lane = t & 63, w = t >> 6;
    int wm = w >> 2, wn = w & 3;
    int lr = lane & 15, lq = lane >> 4;
    int lin = blockIdx.x;
    int cpx = gridDim.x >> 3;          // bijective XCD-chunked swizzle (grid % 8 == 0)
    int wg = (lin & 7) * cpx + (lin >> 3);
    int bm = wg / nbn, bn = wg % nbn;
    const bf16* Ab = A + (size_t)bm * 256 * K;
    const bf16* Bb = BT + (size_t)bn * BN * K;

    auto stA = [&](int slot, int kt, int piece) {
        int idx = piece * 512 + t;
        int r = idx >> 3, c8 = idx & 7;
        gload_lds16(Ab + (size_t)r * K + kt * 64 + ((c8 ^ (r & 7)) * 8), &As[slot][idx * 8]);
    };
    auto stB = [&](int slot, int kt, int piece) {
        int idx = piece * 512 + t;
        int r = idx >> 3, c8 = idx & 7;
        gload_lds16(Bb + (size_t)r * K + kt * 64 + ((c8 ^ (r & 7)) * 8), &Bs[slot][idx * 8]);
    };

    f32x4 acc[8][NFRAG] = {};
    bf16x8 bq[NFRAG][2], af[2][2];

    auto readB = [&](int slot) {
#pragma unroll
        for (int n = 0; n < NFRAG; ++n)
#pragma unroll
            for (int ks = 0; ks < 2; ++ks) {
                int ro = wn * (NFRAG * 16) + n * 16 + lr;
                int ch = (ks * 4 + lq) ^ (ro & 7);
                bq[n][ks] = *reinterpret_cast<const bf16x8*>(&Bs[slot][ro * 64 + ch * 8]);
            }
    };
    auto readA = [&](int mbase, int slot) {
#pragma unroll
        for (int mi = 0; mi < 2; ++mi)
#pragma unroll
            for (int ks = 0; ks < 2; ++ks) {
                int ro = wm * 128 + (mbase + mi) * 16 + lr;
                int ch = (ks * 4 + lq) ^ (ro & 7);
                af[mi][ks] = *reinterpret_cast<const bf16x8*>(&As[slot][ro * 64 + ch * 8]);
            }
    };
    auto mf = [&](int mbase) {
#pragma unroll
        for (int mi = 0; mi < 2; ++mi)
#pragma unroll
            for (int n = 0; n < NFRAG; ++n)
#pragma unroll
                for (int ks = 0; ks < 2; ++ks)
                    acc[mbase + mi][n] = MFMA16(af[mi][ks], bq[n][ks], acc[mbase + mi][n]);
    };

#define GATE_PB()                                                          \
    do {                                                                   \
        if constexpr (NFRAG == 4) asm volatile("s_waitcnt vmcnt(4)" ::: "memory"); \
        else                      asm volatile("s_waitcnt vmcnt(3)" ::: "memory"); \
    } while (0)
#define PHASE_TAIL()                                                       \
    do {                                                                   \
        __builtin_amdgcn_s_barrier();                                      \
        asm volatile("s_waitcnt lgkmcnt(0)" ::: "memory");                 \
    } while (0)
#define MFMA_CLUSTER(mb)                                                   \
    do {                                                                   \
        __builtin_amdgcn_s_setprio(1);                                     \
        mf(mb);                                                            \
        __builtin_amdgcn_s_setprio(0);                                     \
        __builtin_amdgcn_s_barrier();                                      \
    } while (0)

    int nkt = K >> 6;
    // ---- prologue: A(0), B(0), B(1); certify tile 0 (leave B(1) in flight) ----
#pragma unroll
    for (int p = 0; p < 4; ++p) stA(0, 0, p);
#pragma unroll
    for (int p = 0; p < PB; ++p) stB(0, 0, p);
#pragma unroll
    for (int p = 0; p < PB; ++p) stB(1, 1, p);
    GATE_PB();
    __builtin_amdgcn_s_barrier();

    int nI = nkt >> 1;
    for (int I = 0; I < nI; ++I) {
        int T = I << 1;
        bool s2 = (T + 2) < nkt, s3 = (T + 3) < nkt;
        // ---- phi1: tile T, m0-1 (+ all B); stage A(T+1) -> slot1 ----
        readB(0); readA(0, 0);
#pragma unroll
        for (int p = 0; p < 4; ++p) stA(1, T + 1, p);
        PHASE_TAIL();
        MFMA_CLUSTER(0);
        // ---- phi2: m2-3; stage B(T+2) pieces 0-1 -> slot0 ----
        readA(2, 0);
        if (s2) { stB(0, T + 2, 0); stB(0, T + 2, 1); }
        PHASE_TAIL();
        MFMA_CLUSTER(2);
        // ---- phi3: m4-5; stage B(T+2) remaining pieces ----
        readA(4, 0);
        if (s2) {
#pragma unroll
            for (int p = 2; p < PB; ++p) stB(0, T + 2, p);
        }
        PHASE_TAIL();
        MFMA_CLUSTER(4);
        // ---- phi4: m6-7; GATE certifies tile T+1 ----
        readA(6, 0);
        if (s2) GATE_PB();
        else    asm volatile("s_waitcnt vmcnt(0)" ::: "memory");
        PHASE_TAIL();
        MFMA_CLUSTER(6);
        // ---- phi5: tile T+1, m0-1 (+ all B); stage A(T+2) -> slot0 ----
        readB(1); readA(0, 1);
        if (s2) {
#pragma unroll
            for (int p = 0; p < 4; ++p) stA(0, T + 2, p);
        }
        PHASE_TAIL();
        MFMA_CLUSTER(0);
        // ---- phi6: m2-3; stage B(T+3) pieces 0-1 -> slot1 ----
        readA(2, 1);
        if (s3) { stB(1, T + 3, 0); stB(1, T + 3, 1); }
        PHASE_TAIL();
        MFMA_CLUSTER(2);
        // ---- phi7: m4-5; stage B(T+3) remaining pieces ----
        readA(4, 1);
        if (s3) {
#pragma unroll
            for (int p = 2; p < PB; ++p) stB(1, T + 3, p);
        }
        PHASE_TAIL();
        MFMA_CLUSTER(4);
        // ---- phi8: m6-7; GATE certifies tile T+2 ----
        readA(6, 1);
        if (s3) GATE_PB();
        else    asm volatile("s_waitcnt vmcnt(0)" ::: "memory");
        PHASE_TAIL();
        MFMA_CLUSTER(6);
    }
#undef GATE_PB
#undef PHASE_TAIL
#undef MFMA_CLUSTER

    // ---- epilogue ----
#pragma unroll
    for (int m = 0; m < 8; ++m)
#pragma unroll
        for (int n = 0; n < NFRAG; ++n) {
            int row = bm * 256 + wm * 128 + m * 16 + lq * 4;
            int col = bn * BN + wn * (NFRAG * 16) + n * 16 + lr;
#pragma unroll
            for (int j = 0; j < 4; ++j) {
                if (OUT_F32)
                    ((float*)Cv)[(size_t)(row + j) * N + col] = acc[m][n][j];
                else
                    ((bf16*)Cv)[(size_t)(row + j) * N + col] = __float2bfloat16(acc[m][n][j]);
            }
        }
}

// ---------------- RMSNorm + RoPE + layout; 1 wave per (row, head-slot) ----------------
// qkv [8192][3072] bf16 -> qh [B][16][L][128] (scaled by SCALE*log2e),
// kh [B][4][L][128] (col XOR-swizzled per row), vt [B][4][128][L] (col-in-64-tile XOR-swizzled)
__global__ __launch_bounds__(256) void normrope_kernel(const bf16* __restrict__ qkv,
                                                       const float* __restrict__ cosT,
                                                       const float* __restrict__ sinT,
                                                       const float* __restrict__ qnw,
                                                       const float* __restrict__ knw,
                                                       bf16* __restrict__ qh,
                                                       bf16* __restrict__ kh,
                                                       bf16* __restrict__ vt) {
    int t = threadIdx.x;
    int lane = t & 63, wv = t >> 6;
    int blk = blockIdx.x;
    int r = blk / 6;
    int s = (blk % 6) * 4 + wv;     // slot 0..23: 0-15 Q heads, 16-19 K groups, 20-23 V groups
    int b = r >> 12, l = r & 4095;
    const bf16* src = qkv + (size_t)r * 3072 + s * 128;
    float x1 = __bfloat162float(src[lane]);
    float x2 = __bfloat162float(src[lane + 64]);
    if (s < 20) {
        float ss = x1 * x1 + x2 * x2;
#pragma unroll
        for (int d = 1; d < 64; d <<= 1) ss += __shfl_xor(ss, d, 64);
        float rn = rsqrtf(ss * (1.0f / 128.0f) + 1e-6f);
        const float* wn = (s < 16) ? qnw : knw;
        float xn1 = x1 * rn * wn[lane];
        float xn2 = x2 * rn * wn[lane + 64];
        float c = cosT[(size_t)l * 128 + lane];
        float sn = sinT[(size_t)l * 128 + lane];
        float o1 = xn1 * c - xn2 * sn;
        float o2 = xn2 * c + xn1 * sn;
        if (s < 16) {
            const float scl = 0.0625f * 1.44269504088896f;  // SCALE * log2(e) folded into q
            bf16* dst = qh + ((size_t)(b * 16 + s) * 4096 + l) * 128;
            dst[lane] = __float2bfloat16(o1 * scl);
            dst[lane + 64] = __float2bfloat16(o2 * scl);
        } else {
            int g = s - 16;
            // pre-swizzled for LDS bank-conflict-free ds_read_b128 in attn (T2 / rule #21)
            int sw = (l & 7) << 3;
            bf16* dst = kh + ((size_t)(b * 4 + g) * 4096 + l) * 128;
            dst[lane ^ sw] = __float2bfloat16(o1);
            dst[(lane + 64) ^ sw] = __float2bfloat16(o2);
        }
    } else {
        int g = s - 20;
        bf16* dst = vt + (size_t)(b * 4 + g) * 128 * 4096;
        int base = l & ~63, cj = l & 63;
        int d1 = lane, d2 = lane + 64;
        int sw = (lane & 7) << 3;   // (d1&7)==(d2&7)
        dst[(size_t)d1 * 4096 + base + (cj ^ sw)] = __float2bfloat16(x1);
        dst[(size_t)d2 * 4096 + base + (cj ^ sw)] = __float2bfloat16(x2);
    }
}

// ---------------- sliding-window flash attention ----------------
// QBLK=128, 8 waves (512 thr), KVBLK=64, dbuf LDS staging, fixed-shift exp2 softmax.
// qh [B][16][L][128] (pre-scaled by SCALE*log2e), kh (swizzled), vt (swizzled) -> ao [B*L][2048]
__global__ __launch_bounds__(512, 4) void attn_kernel(const bf16* __restrict__ qh,
                                                      const bf16* __restrict__ kh,
                                                      const bf16* __restrict__ vt,
                                                      bf16* __restrict__ ao) {
    __shared__ bf16 Ks[2][64 * 128];    // 32 KiB
    __shared__ bf16 Vs[2][128 * 64];    // 32 KiB
    __shared__ bf16 P_lds[8][16][64];   // 16 KiB (XOR-swizzled, no pad) -> 80 KiB total
    int t = threadIdx.x;
    int lane = t & 63, w = t >> 6;
    int lr = lane & 15, lq = lane >> 4;
    int qs = blockIdx.x * 128;
    int bh = blockIdx.y;
    int b = bh >> 4, h = bh & 15, g = h >> 2;
    const bf16* qp = qh + ((size_t)(b * 16 + h) * 4096 + qs + w * 16) * 128;
    const bf16* kp = kh + (size_t)(b * 4 + g) * 4096 * 128;
    const bf16* vp = vt + (size_t)(b * 4 + g) * 128 * 4096;

    bf16x8 aq[4];
#pragma unroll
    for (int kk = 0; kk < 4; ++kk)
        aq[kk] = *reinterpret_cast<const bf16x8*>(qp + (size_t)lr * 128 + kk * 32 + lq * 8);

    f32x4 o[8] = {};
    float lsum[4] = {0.f, 0.f, 0.f, 0.f};
    int row0 = qs + w * 16;                      // wave's first q row
    int iq0 = row0 + lq * 4;
    int t0w = max(0, row0 - 1023) >> 6;          // wave's first needed tile
    int t1w = row0 >> 6;                         // wave's diagonal tile
    int t0 = max(0, qs - 1023) >> 6;             // block-level range
    int t1 = (qs + 112) >> 6;

    auto stage = [&](int buf, int kt) {
        int j0 = kt * 64;
        const bf16* kg = kp + (size_t)j0 * 128;  // contiguous 16 KB (pre-swizzled)
#pragma unroll
        for (int i = 0; i < 2; ++i) {
            int c = i * 512 + t;                 // 0..1023 chunks of 16B
            gload_lds16(kg + c * 8, &Ks[buf][c * 8]);
        }
#pragma unroll
        for (int i = 0; i < 2; ++i) {
            int c = i * 512 + t;
            int d = c >> 3, co = (c & 7) * 8;
            gload_lds16(vp + (size_t)d * 4096 + j0 + co, &Vs[buf][c * 8]);
        }
    };

    stage(0, t0);
    __syncthreads();   // compiler emits vmcnt(0) drain before s_barrier
    int cur = 0;

    for (int kt = t0; kt <= t1; ++kt) {
        int j0 = kt * 64;
        if (kt < t1) stage(cur ^ 1, kt + 1);     // prefetch overlaps compute (all waves)
        if (kt >= t0w && kt <= t1w) {            // wave-uniform activity window
            // ---- S = Q K^T from LDS (swizzled reads) ----
            f32x4 s[4] = {};
            __builtin_amdgcn_s_setprio(1);
#pragma unroll
            for (int jt = 0; jt < 4; ++jt) {
                int r = jt * 16 + lr;
                int rs = (r & 7) << 3;
#pragma unroll
                for (int kk = 0; kk < 4; ++kk) {
                    int c = kk * 32 + lq * 8;
                    bf16x8 bk = *reinterpret_cast<const bf16x8*>(&Ks[cur][r * 128 + (c ^ rs)]);
                    s[jt] = MFMA16(aq[kk], bk, s[jt]);
                }
            }
            __builtin_amdgcn_s_setprio(0);
            // ---- sliding-window causal mask: only wave-boundary tiles ----
            if (kt <= t0w + 1 || kt == t1w) {
#pragma unroll
                for (int jt = 0; jt < 4; ++jt)
#pragma unroll
                    for (int j = 0; j < 4; ++j) {
                        int qi = iq0 + j;
                        int kj = j0 + jt * 16 + lr;
                        if (!(kj <= qi && kj > qi - 1024)) s[jt][j] = -1e30f;
                    }
            }
            // ---- fixed-shift softmax in log2 space: p = exp2(s - 11.54); sum deferred ----
#pragma unroll
            for (int jt = 0; jt < 4; ++jt)
#pragma unroll
                for (int j = 0; j < 4; ++j) {
                    float p = exp2f(s[jt][j] - 11.5415603f);
                    lsum[j] += p;
                    int row = lq * 4 + j;
                    P_lds[w][row][(jt * 16 + lr) ^ ((row & 7) << 3)] = __float2bfloat16(p);
                }
            // ---- O += P V (V from LDS, swizzled reads) ----
            __builtin_amdgcn_s_setprio(1);
#pragma unroll
            for (int kk2 = 0; kk2 < 2; ++kk2) {
                bf16x8 pa = *reinterpret_cast<const bf16x8*>(
                    &P_lds[w][lr][(kk2 * 32 + lq * 8) ^ ((lr & 7) << 3)]);
#pragma unroll
                for (int dt = 0; dt < 8; ++dt) {
                    int r = dt * 16 + lr;
                    int c = kk2 * 32 + lq * 8;
                    bf16x8 bv = *reinterpret_cast<const bf16x8*>(&Vs[cur][r * 64 + (c ^ ((r & 7) << 3))]);
                    o[dt] = MFMA16(pa, bv, o[dt]);
                }
            }
            __builtin_amdgcn_s_setprio(0);
        }
        __syncthreads();   // drains staging vmcnt; all waves done with buf[cur]
        cur ^= 1;
    }
    // ---- final row-sum reduce (once, not per tile) ----
    float linv[4];
#pragma unroll
    for (int j = 0; j < 4; ++j) {
        float l = lsum[j];
        l += __shfl_xor(l, 1, 64);
        l += __shfl_xor(l, 2, 64);
        l += __shfl_xor(l, 4, 64);
        l += __shfl_xor(l, 8, 64);
        linv[j] = 1.0f / l;
    }
    // ---- epilogue: O / l, write [B*L][16*128] ----
#pragma unroll
    for (int dt = 0; dt < 8; ++dt)
#pragma unroll
        for (int j = 0; j < 4; ++j) {
            float val = o[dt][j] * linv[j];
            ao[((size_t)(b * 4096 + qs + w * 16 + lq * 4 + j)) * 2048 + h * 128 + dt * 16 + lr] =
                __float2bfloat16(val);
        }
}

extern "C" void kernel_launch(void* const* d_in, const int* in_sizes, int n_in,
                              void* d_out, int out_size, void* d_ws, size_t ws_size,
                              hipStream_t stream) {
    const float* x    = (const float*)d_in[0];
    const float* cosT = (const float*)d_in[1];
    const float* sinT = (const float*)d_in[2];
    const float* Wq   = (const float*)d_in[3];
    const float* Wk   = (const float*)d_in[4];
    const float* Wv   = (const float*)d_in[5];
    const float* Wo   = (const float*)d_in[6];
    const float* qnw  = (const float*)d_in[7];
    const float* knw  = (const float*)d_in[8];

    char* ws = (char*)d_ws;
    bf16* xb    = (bf16*)(ws);                 // 33,554,432 B  [8192][2048]
    bf16* wqkvT = (bf16*)(ws + 33554432);      // 12,582,912 B  [3072][2048]
    bf16* woT   = (bf16*)(ws + 46137344);      //  8,388,608 B  [2048][2048]
    bf16* qh    = (bf16*)(ws + 54525952);      // 33,554,432 B  [2][16][4096][128]
    bf16* kh    = (bf16*)(ws + 88080384);      //  8,388,608 B  [2][4][4096][128]
    bf16* vt    = (bf16*)(ws + 96468992);      //  8,388,608 B  [2][4][128][4096] -> total 100 MiB
    bf16* ao    = xb;                          // alias: xb dead after GEMM1
    bf16* qkv   = (bf16*)d_out;                // d_out as scratch: overwritten by GEMM2

    cvt_bf16_kernel<<<8192, 256, 0, stream>>>(x, xb, 16777216);
    transpose_wqkv_kernel<<<dim3(64, 96), 256, 0, stream>>>(Wq, Wk, Wv, wqkvT);
    transpose_w_kernel<<<dim3(64, 64), 256, 0, stream>>>(Wo, woT);
    // GEMM1: 256x192 tiles -> 32x16 = 512 blocks = exactly 2 full rounds (no tail)
    gemm8p_kernel<3, false><<<512, 512, 0, stream>>>(xb, wqkvT, (void*)qkv, 8192, 3072, 2048, 16);
    normrope_kernel<<<49152, 256, 0, stream>>>(qkv, cosT, sinT, qnw, knw, qh, kh, vt);
    attn_kernel<<<dim3(32, 32), 512, 0, stream>>>(qh, kh, vt, ao);
    // GEMM2: 256x256 tiles -> 32x8 = 256 blocks = exactly 1 round
    gemm8p_kernel<4, true><<<256, 512, 0, stream>>>(ao, woT, d_out, 8192, 2048, 2048, 8);
}

// Round 6
// 357.039 us; speedup vs baseline: 2.1935x; 1.0137x over previous
//
#include <hip/hip_runtime.h>
#include <hip/hip_bf16.h>

typedef __hip_bfloat16 bf16;
typedef __attribute__((ext_vector_type(8))) __bf16 bf16x8;
typedef __attribute__((ext_vector_type(4))) float f32x4;

#define MFMA16(a, b, c) __builtin_amdgcn_mfma_f32_16x16x32_bf16((a), (b), (c), 0, 0, 0)

static __device__ __forceinline__ void gload_lds16(const void* g, void* l) {
    typedef const __attribute__((address_space(1))) unsigned gq_t;
    typedef __attribute__((address_space(3))) unsigned ls_t;
    __builtin_amdgcn_global_load_lds((gq_t*)g, (ls_t*)l, 16, 0, 0);
}

static __device__ __forceinline__ unsigned short f2bfbits(float f) {
    bf16 h = __float2bfloat16(f);
    return *reinterpret_cast<unsigned short*>(&h);
}

// ---------------- prepass: f32 -> bf16 cast of x ----------------
__global__ __launch_bounds__(256) void cvt_bf16_kernel(const float* __restrict__ in,
                                                       bf16* __restrict__ out, int n) {
    int i = (blockIdx.x * 256 + threadIdx.x) * 8;
    if (i < n) {
        float4 a = *reinterpret_cast<const float4*>(in + i);
        float4 b = *reinterpret_cast<const float4*>(in + i + 4);
        bf16 tmp[8];
        tmp[0] = __float2bfloat16(a.x); tmp[1] = __float2bfloat16(a.y);
        tmp[2] = __float2bfloat16(a.z); tmp[3] = __float2bfloat16(a.w);
        tmp[4] = __float2bfloat16(b.x); tmp[5] = __float2bfloat16(b.y);
        tmp[6] = __float2bfloat16(b.z); tmp[7] = __float2bfloat16(b.w);
        *reinterpret_cast<uint4*>(out + i) = *reinterpret_cast<const uint4*>(tmp);
    }
}

// ---------------- prepass: transpose Wq|Wk|Wv -> [3072][2048] bf16 ----------------
__global__ __launch_bounds__(256) void transpose_wqkv_kernel(const float* __restrict__ Wq,
                                                             const float* __restrict__ Wk,
                                                             const float* __restrict__ Wv,
                                                             bf16* __restrict__ out) {
    __shared__ float tile[32][33];
    int k0 = blockIdx.x * 32;   // along K (2048)
    int n0 = blockIdx.y * 32;   // along N (3072)
    int tx = threadIdx.x & 31, ty = threadIdx.x >> 5;  // 32 x 8
#pragma unroll
    for (int i = 0; i < 4; ++i) {
        int k = k0 + ty + i * 8, n = n0 + tx;
        float v;
        if (n < 2048)      v = Wq[(size_t)k * 2048 + n];
        else if (n < 2560) v = Wk[(size_t)k * 512 + (n - 2048)];
        else               v = Wv[(size_t)k * 512 + (n - 2560)];
        tile[ty + i * 8][tx] = v;
    }
    __syncthreads();
#pragma unroll
    for (int i = 0; i < 4; ++i)
        out[(size_t)(n0 + ty + i * 8) * 2048 + k0 + tx] = __float2bfloat16(tile[tx][ty + i * 8]);
}

// ---------------- prepass: transpose square W (2048x2048) -> bf16 ----------------
__global__ __launch_bounds__(256) void transpose_w_kernel(const float* __restrict__ in,
                                                          bf16* __restrict__ out) {
    __shared__ float tile[32][33];
    int k0 = blockIdx.x * 32, n0 = blockIdx.y * 32;
    int tx = threadIdx.x & 31, ty = threadIdx.x >> 5;
#pragma unroll
    for (int i = 0; i < 4; ++i)
        tile[ty + i * 8][tx] = in[(size_t)(k0 + ty + i * 8) * 2048 + n0 + tx];
    __syncthreads();
#pragma unroll
    for (int i = 0; i < 4; ++i)
        out[(size_t)(n0 + ty + i * 8) * 2048 + k0 + tx] = __float2bfloat16(tile[tx][ty + i * 8]);
}

// ---------------- 8-phase GEMM template (m201-faithful): C = A[M,K] @ BT[N,K]^T ----------------
template <int NFRAG, bool OUT_F32>
__global__ __launch_bounds__(512, 2) void gemm8p_kernel(const bf16* __restrict__ A,
                                                        const bf16* __restrict__ BT,
                                                        void* __restrict__ Cv,
                                                        int M, int N, int K, int nbn) {
    constexpr int BN = NFRAG * 64;
    constexpr int PB = NFRAG;          // B pieces per K-tile (1 gload/thread each)
    __shared__ bf16 As[2][256 * 64];
    __shared__ bf16 Bs[2][BN * 64];
    int t = threadIdx.x;
    int lane = t & 63, w = t >> 6;
    int wm = w >> 2, wn = w & 3;
    int lr = lane & 15, lq = lane >> 4;
    int lin = blockIdx.x;
    int cpx = gridDim.x >> 3;          // bijective XCD-chunked swizzle (grid % 8 == 0)
    int wg = (lin & 7) * cpx + (lin >> 3);
    int bm = wg / nbn, bn = wg % nbn;
    const bf16* Ab = A + (size_t)bm * 256 * K;
    const bf16* Bb = BT + (size_t)bn * BN * K;

    auto stA = [&](int slot, int kt, int piece) {
        int idx = piece * 512 + t;
        int r = idx >> 3, c8 = idx & 7;
        gload_lds16(Ab + (size_t)r * K + kt * 64 + ((c8 ^ (r & 7)) * 8), &As[slot][idx * 8]);
    };
    auto stB = [&](int slot, int kt, int piece) {
        int idx = piece * 512 + t;
        int r = idx >> 3, c8 = idx & 7;
        gload_lds16(Bb + (size_t)r * K + kt * 64 + ((c8 ^ (r & 7)) * 8), &Bs[slot][idx * 8]);
    };

    f32x4 acc[8][NFRAG] = {};
    bf16x8 bq[NFRAG][2], af[2][2];

    auto readB = [&](int slot) {
#pragma unroll
        for (int n = 0; n < NFRAG; ++n)
#pragma unroll
            for (int ks = 0; ks < 2; ++ks) {
                int ro = wn * (NFRAG * 16) + n * 16 + lr;
                int ch = (ks * 4 + lq) ^ (ro & 7);
                bq[n][ks] = *reinterpret_cast<const bf16x8*>(&Bs[slot][ro * 64 + ch * 8]);
            }
    };
    auto readA = [&](int mbase, int slot) {
#pragma unroll
        for (int mi = 0; mi < 2; ++mi)
#pragma unroll
            for (int ks = 0; ks < 2; ++ks) {
                int ro = wm * 128 + (mbase + mi) * 16 + lr;
                int ch = (ks * 4 + lq) ^ (ro & 7);
                af[mi][ks] = *reinterpret_cast<const bf16x8*>(&As[slot][ro * 64 + ch * 8]);
            }
    };
    auto mf = [&](int mbase) {
#pragma unroll
        for (int mi = 0; mi < 2; ++mi)
#pragma unroll
            for (int n = 0; n < NFRAG; ++n)
#pragma unroll
                for (int ks = 0; ks < 2; ++ks)
                    acc[mbase + mi][n] = MFMA16(af[mi][ks], bq[n][ks], acc[mbase + mi][n]);
    };

#define GATE_PB()                                                          \
    do {                                                                   \
        if constexpr (NFRAG == 4) asm volatile("s_waitcnt vmcnt(4)" ::: "memory"); \
        else                      asm volatile("s_waitcnt vmcnt(3)" ::: "memory"); \
    } while (0)
#define PHASE_TAIL()                                                       \
    do {                                                                   \
        __builtin_amdgcn_s_barrier();                                      \
        asm volatile("s_waitcnt lgkmcnt(0)" ::: "memory");                 \
    } while (0)
#define MFMA_CLUSTER(mb)                                                   \
    do {                                                                   \
        __builtin_amdgcn_s_setprio(1);                                     \
        mf(mb);                                                            \
        __builtin_amdgcn_s_setprio(0);                                     \
        __builtin_amdgcn_s_barrier();                                      \
    } while (0)

    int nkt = K >> 6;
    // ---- prologue: A(0), B(0), B(1); certify tile 0 (leave B(1) in flight) ----
#pragma unroll
    for (int p = 0; p < 4; ++p) stA(0, 0, p);
#pragma unroll
    for (int p = 0; p < PB; ++p) stB(0, 0, p);
#pragma unroll
    for (int p = 0; p < PB; ++p) stB(1, 1, p);
    GATE_PB();
    __builtin_amdgcn_s_barrier();

    int nI = nkt >> 1;
    for (int I = 0; I < nI; ++I) {
        int T = I << 1;
        bool s2 = (T + 2) < nkt, s3 = (T + 3) < nkt;
        // ---- phi1: tile T, m0-1 (+ all B); stage A(T+1) -> slot1 ----
        readB(0); readA(0, 0);
#pragma unroll
        for (int p = 0; p < 4; ++p) stA(1, T + 1, p);
        PHASE_TAIL();
        MFMA_CLUSTER(0);
        // ---- phi2: m2-3; stage B(T+2) pieces 0-1 -> slot0 ----
        readA(2, 0);
        if (s2) { stB(0, T + 2, 0); stB(0, T + 2, 1); }
        PHASE_TAIL();
        MFMA_CLUSTER(2);
        // ---- phi3: m4-5; stage B(T+2) remaining pieces ----
        readA(4, 0);
        if (s2) {
#pragma unroll
            for (int p = 2; p < PB; ++p) stB(0, T + 2, p);
        }
        PHASE_TAIL();
        MFMA_CLUSTER(4);
        // ---- phi4: m6-7; GATE certifies tile T+1 ----
        readA(6, 0);
        if (s2) GATE_PB();
        else    asm volatile("s_waitcnt vmcnt(0)" ::: "memory");
        PHASE_TAIL();
        MFMA_CLUSTER(6);
        // ---- phi5: tile T+1, m0-1 (+ all B); stage A(T+2) -> slot0 ----
        readB(1); readA(0, 1);
        if (s2) {
#pragma unroll
            for (int p = 0; p < 4; ++p) stA(0, T + 2, p);
        }
        PHASE_TAIL();
        MFMA_CLUSTER(0);
        // ---- phi6: m2-3; stage B(T+3) pieces 0-1 -> slot1 ----
        readA(2, 1);
        if (s3) { stB(1, T + 3, 0); stB(1, T + 3, 1); }
        PHASE_TAIL();
        MFMA_CLUSTER(2);
        // ---- phi7: m4-5; stage B(T+3) remaining pieces ----
        readA(4, 1);
        if (s3) {
#pragma unroll
            for (int p = 2; p < PB; ++p) stB(1, T + 3, p);
        }
        PHASE_TAIL();
        MFMA_CLUSTER(4);
        // ---- phi8: m6-7; GATE certifies tile T+2 ----
        readA(6, 1);
        if (s3) GATE_PB();
        else    asm volatile("s_waitcnt vmcnt(0)" ::: "memory");
        PHASE_TAIL();
        MFMA_CLUSTER(6);
    }
#undef GATE_PB
#undef PHASE_TAIL
#undef MFMA_CLUSTER

    // ---- epilogue ----
#pragma unroll
    for (int m = 0; m < 8; ++m)
#pragma unroll
        for (int n = 0; n < NFRAG; ++n) {
            int row = bm * 256 + wm * 128 + m * 16 + lq * 4;
            int col = bn * BN + wn * (NFRAG * 16) + n * 16 + lr;
#pragma unroll
            for (int j = 0; j < 4; ++j) {
                if (OUT_F32)
                    ((float*)Cv)[(size_t)(row + j) * N + col] = acc[m][n][j];
                else
                    ((bf16*)Cv)[(size_t)(row + j) * N + col] = __float2bfloat16(acc[m][n][j]);
            }
        }
}

// ---------------- RMSNorm + RoPE + layout; 1 wave per (row, head-slot) ----------------
// Vectorized: lane holds elems (2*lane, 2*lane+1); RoPE partner via shfl_xor(32).
// qkv [8192][3072] bf16 -> qh [B][16][L][128] (scaled by SCALE*log2e),
// kh [B][4][L][128] (col XOR-swizzled per row),
// vt [B][4][128][L]: col = (l&~63) + (sigma(l&63) ^ ((d&7)<<3)) where sigma is the
//   k-slot bit-permutation matching attn's in-register P fragment order:
//   sigma: p5=k5, p4=k3, p3=k2, p2=k4, p1=k1, p0=k0.
__global__ __launch_bounds__(256) void normrope_kernel(const bf16* __restrict__ qkv,
                                                       const float* __restrict__ cosT,
                                                       const float* __restrict__ sinT,
                                                       const float* __restrict__ qnw,
                                                       const float* __restrict__ knw,
                                                       bf16* __restrict__ qh,
                                                       bf16* __restrict__ kh,
                                                       bf16* __restrict__ vt) {
    int t = threadIdx.x;
    int lane = t & 63, wv = t >> 6;
    int blk = blockIdx.x;
    int r = blk / 6;
    int s = (blk % 6) * 4 + wv;     // slot 0..23: 0-15 Q heads, 16-19 K groups, 20-23 V groups
    int b = r >> 12, l = r & 4095;
    int e0 = lane * 2;
    const bf16* src = qkv + (size_t)r * 3072 + s * 128;
    ushort2 xu = *reinterpret_cast<const ushort2*>(src + e0);
    float v0 = __uint_as_float((unsigned)xu.x << 16);
    float v1 = __uint_as_float((unsigned)xu.y << 16);
    if (s < 20) {
        float ss = v0 * v0 + v1 * v1;
#pragma unroll
        for (int d = 1; d < 64; d <<= 1) ss += __shfl_xor(ss, d, 64);
        float rn = rsqrtf(ss * (1.0f / 128.0f) + 1e-6f);
        const float* wn = (s < 16) ? qnw : knw;
        float2 wv2 = *reinterpret_cast<const float2*>(wn + e0);
        float xn0 = v0 * rn * wv2.x;
        float xn1 = v1 * rn * wv2.y;
        float xp0 = __shfl_xor(xn0, 32, 64);
        float xp1 = __shfl_xor(xn1, 32, 64);
        float r0 = (lane < 32) ? -xp0 : xp0;
        float r1 = (lane < 32) ? -xp1 : xp1;
        float2 c2 = *reinterpret_cast<const float2*>(cosT + (size_t)l * 128 + e0);
        float2 s2 = *reinterpret_cast<const float2*>(sinT + (size_t)l * 128 + e0);
        float o0 = xn0 * c2.x + r0 * s2.x;
        float o1 = xn1 * c2.y + r1 * s2.y;
        ushort2 ou;
        if (s < 16) {
            const float scl = 0.0625f * 1.44269504088896f;  // SCALE * log2(e) folded into q
            ou.x = f2bfbits(o0 * scl);
            ou.y = f2bfbits(o1 * scl);
            bf16* dst = qh + ((size_t)(b * 16 + s) * 4096 + l) * 128;
            *reinterpret_cast<ushort2*>(dst + e0) = ou;
        } else {
            int g = s - 16;
            ou.x = f2bfbits(o0);
            ou.y = f2bfbits(o1);
            int sw = (l & 7) << 3;   // bits >=3: pair adjacency + 4B alignment preserved
            bf16* dst = kh + ((size_t)(b * 4 + g) * 4096 + l) * 128;
            *reinterpret_cast<ushort2*>(dst + (e0 ^ sw)) = ou;
        }
    } else {
        int g = s - 20;
        bf16* dst = vt + (size_t)(b * 4 + g) * 128 * 4096;
        int base = l & ~63, cj = l & 63;
        int pos = (cj & 0x23) | ((cj & 16) >> 2) | ((cj & 12) << 1);  // sigma(cj)
        int d0 = e0, d1 = e0 + 1;
        dst[(size_t)d0 * 4096 + base + (pos ^ ((d0 & 7) << 3))] = __float2bfloat16(v0);
        dst[(size_t)d1 * 4096 + base + (pos ^ ((d1 & 7) << 3))] = __float2bfloat16(v1);
    }
}

// ---------------- sliding-window flash attention ----------------
// QBLK=128, 8 waves, KVBLK=64, dbuf LDS staging, fixed-shift exp2 softmax.
// Swapped QK^T: s = mfma(K_frag, Q_frag) -> lane holds P[q=lr][k=jt*16+lq*4+j].
// P fragment assembled IN-REGISTER via v_cvt_pk_bf16_f32 (no P_lds round trip);
// V's k-order is pre-permuted in vt (sigma) so the b128 V reads match the fragment order.
__global__ __launch_bounds__(512, 4) void attn_kernel(const bf16* __restrict__ qh,
                                                      const bf16* __restrict__ kh,
                                                      const bf16* __restrict__ vt,
                                                      bf16* __restrict__ ao) {
    __shared__ bf16 Ks[2][64 * 128];    // 32 KiB
    __shared__ bf16 Vs[2][128 * 64];    // 32 KiB -> 64 KiB total
    int t = threadIdx.x;
    int lane = t & 63, w = t >> 6;
    int lr = lane & 15, lq = lane >> 4;
    int qs = blockIdx.x * 128;
    int bh = blockIdx.y;
    int b = bh >> 4, h = bh & 15, g = h >> 2;
    const bf16* qp = qh + ((size_t)(b * 16 + h) * 4096 + qs + w * 16) * 128;
    const bf16* kp = kh + (size_t)(b * 4 + g) * 4096 * 128;
    const bf16* vp = vt + (size_t)(b * 4 + g) * 128 * 4096;

    bf16x8 aq[4];
#pragma unroll
    for (int kk = 0; kk < 4; ++kk)
        aq[kk] = *reinterpret_cast<const bf16x8*>(qp + (size_t)lr * 128 + kk * 32 + lq * 8);

    f32x4 o[8] = {};
    float lsum = 0.f;
    int row0 = qs + w * 16;                      // wave's first q row
    int qi = row0 + lr;                          // this lane's q row (S^T layout)
    int t0w = max(0, row0 - 1023) >> 6;          // wave's first needed tile
    int t1w = row0 >> 6;                         // wave's diagonal tile
    int t0 = max(0, qs - 1023) >> 6;             // block-level range
    int t1 = (qs + 112) >> 6;

    auto stage = [&](int buf, int kt) {
        int j0 = kt * 64;
        const bf16* kg = kp + (size_t)j0 * 128;  // contiguous 16 KB (pre-swizzled)
#pragma unroll
        for (int i = 0; i < 2; ++i) {
            int c = i * 512 + t;                 // 0..1023 chunks of 16B
            gload_lds16(kg + c * 8, &Ks[buf][c * 8]);
        }
#pragma unroll
        for (int i = 0; i < 2; ++i) {
            int c = i * 512 + t;
            int d = c >> 3, co = (c & 7) * 8;
            gload_lds16(vp + (size_t)d * 4096 + j0 + co, &Vs[buf][c * 8]);
        }
    };

    stage(0, t0);
    __syncthreads();
    int cur = 0;

    for (int kt = t0; kt <= t1; ++kt) {
        int j0 = kt * 64;
        if (kt < t1) stage(cur ^ 1, kt + 1);     // prefetch overlaps compute (all waves)
        if (kt >= t0w && kt <= t1w) {            // wave-uniform activity window
            // ---- S^T = K Q^T from LDS (swapped operands; scale pre-folded into Q) ----
            f32x4 s[4] = {};
            __builtin_amdgcn_s_setprio(1);
#pragma unroll
            for (int jt = 0; jt < 4; ++jt) {
                int r = jt * 16 + lr;
                int rs = (r & 7) << 3;
#pragma unroll
                for (int kk = 0; kk < 4; ++kk) {
                    int c = kk * 32 + lq * 8;
                    bf16x8 bk = *reinterpret_cast<const bf16x8*>(&Ks[cur][r * 128 + (c ^ rs)]);
                    s[jt] = MFMA16(bk, aq[kk], s[jt]);   // A=K rows, B=Q cols
                }
            }
            __builtin_amdgcn_s_setprio(0);
            // ---- sliding-window causal mask: only wave-boundary tiles ----
            if (kt <= t0w + 1 || kt == t1w) {
#pragma unroll
                for (int jt = 0; jt < 4; ++jt)
#pragma unroll
                    for (int j = 0; j < 4; ++j) {
                        int kj = j0 + jt * 16 + lq * 4 + j;
                        if (!(kj <= qi && kj > qi - 1024)) s[jt][j] = -1e30f;
                    }
            }
            // ---- fixed-shift softmax + in-register bf16 pack (8 cvt_pk, no LDS) ----
            unsigned pk[4][2];
#pragma unroll
            for (int jt = 0; jt < 4; ++jt)
#pragma unroll
                for (int hh = 0; hh < 2; ++hh) {
                    float p0 = exp2f(s[jt][2 * hh] - 11.5415603f);
                    float p1 = exp2f(s[jt][2 * hh + 1] - 11.5415603f);
                    lsum += p0 + p1;
                    asm("v_cvt_pk_bf16_f32 %0, %1, %2" : "=v"(pk[jt][hh]) : "v"(p0), "v"(p1));
                }
            // ---- O += P V (V from LDS, sigma-ordered so slots match) ----
            __builtin_amdgcn_s_setprio(1);
#pragma unroll
            for (int kk2 = 0; kk2 < 2; ++kk2) {
                union { unsigned u[4]; bf16x8 v; } pu;
                pu.u[0] = pk[2 * kk2][0];
                pu.u[1] = pk[2 * kk2][1];
                pu.u[2] = pk[2 * kk2 + 1][0];
                pu.u[3] = pk[2 * kk2 + 1][1];
#pragma unroll
                for (int dt = 0; dt < 8; ++dt) {
                    int r = dt * 16 + lr;
                    int c = kk2 * 32 + lq * 8;
                    bf16x8 bv = *reinterpret_cast<const bf16x8*>(&Vs[cur][r * 64 + (c ^ ((r & 7) << 3))]);
                    o[dt] = MFMA16(pu.v, bv, o[dt]);
                }
            }
            __builtin_amdgcn_s_setprio(0);
        }
        __syncthreads();   // drains staging vmcnt; all waves done with buf[cur]
        cur ^= 1;
    }
    // ---- final row-sum reduce: lane holds partial for q-row lr; reduce over lq ----
    float lt = lsum;
    lt += __shfl_xor(lt, 16, 64);
    lt += __shfl_xor(lt, 32, 64);
    float linv = 1.0f / lt;                      // valid for q-row lr (all lq copies equal)
    float lv[4];
#pragma unroll
    for (int j = 0; j < 4; ++j)
        lv[j] = __shfl(linv, lq * 4 + j, 64);    // linv for output row lq*4+j
    // ---- epilogue: O / l, write [B*L][16*128] ----
#pragma unroll
    for (int dt = 0; dt < 8; ++dt)
#pragma unroll
        for (int j = 0; j < 4; ++j) {
            float val = o[dt][j] * lv[j];
            ao[((size_t)(b * 4096 + row0 + lq * 4 + j)) * 2048 + h * 128 + dt * 16 + lr] =
                __float2bfloat16(val);
        }
}

extern "C" void kernel_launch(void* const* d_in, const int* in_sizes, int n_in,
                              void* d_out, int out_size, void* d_ws, size_t ws_size,
                              hipStream_t stream) {
    const float* x    = (const float*)d_in[0];
    const float* cosT = (const float*)d_in[1];
    const float* sinT = (const float*)d_in[2];
    const float* Wq   = (const float*)d_in[3];
    const float* Wk   = (const float*)d_in[4];
    const float* Wv   = (const float*)d_in[5];
    const float* Wo   = (const float*)d_in[6];
    const float* qnw  = (const float*)d_in[7];
    const float* knw  = (const float*)d_in[8];

    char* ws = (char*)d_ws;
    bf16* xb    = (bf16*)(ws);                 // 33,554,432 B  [8192][2048]
    bf16* wqkvT = (bf16*)(ws + 33554432);      // 12,582,912 B  [3072][2048]
    bf16* woT   = (bf16*)(ws + 46137344);      //  8,388,608 B  [2048][2048]
    bf16* qh    = (bf16*)(ws + 54525952);      // 33,554,432 B  [2][16][4096][128]
    bf16* kh    = (bf16*)(ws + 88080384);      //  8,388,608 B  [2][4][4096][128]
    bf16* vt    = (bf16*)(ws + 96468992);      //  8,388,608 B  [2][4][128][4096] -> total 100 MiB
    bf16* ao    = xb;                          // alias: xb dead after GEMM1
    bf16* qkv   = (bf16*)d_out;                // d_out as scratch: overwritten by GEMM2

    cvt_bf16_kernel<<<8192, 256, 0, stream>>>(x, xb, 16777216);
    transpose_wqkv_kernel<<<dim3(64, 96), 256, 0, stream>>>(Wq, Wk, Wv, wqkvT);
    transpose_w_kernel<<<dim3(64, 64), 256, 0, stream>>>(Wo, woT);
    // GEMM1: 256x192 tiles -> 32x16 = 512 blocks = exactly 2 full rounds (no tail)
    gemm8p_kernel<3, false><<<512, 512, 0, stream>>>(xb, wqkvT, (void*)qkv, 8192, 3072, 2048, 16);
    normrope_kernel<<<49152, 256, 0, stream>>>(qkv, cosT, sinT, qnw, knw, qh, kh, vt);
    attn_kernel<<<dim3(32, 32), 512, 0, stream>>>(qh, kh, vt, ao);
    // GEMM2: 256x256 tiles -> 32x8 = 256 blocks = exactly 1 round
    gemm8p_kernel<4, true><<<256, 512, 0, stream>>>(ao, woT, d_out, 8192, 2048, 2048, 8);
}